// Round 6
// baseline (790.258 us; speedup 1.0000x reference)
//
#include <hip/hip_runtime.h>
#include <math.h>

#define TOK 4096
#define DM 2048
#define DQ 682
#define DQP 704
#define DKV 1024
#define DUKV 3072
#define NH 16
#define T_SEQ 2048
#define NQKV 1792   // 704 (padded Wdq) + 1088 (Wdkv)

typedef __attribute__((ext_vector_type(8))) short short8;
typedef __attribute__((ext_vector_type(4))) float floatx4;
typedef __attribute__((ext_vector_type(4))) unsigned short ushort4v;
typedef __attribute__((ext_vector_type(2))) unsigned int uint2v;

__device__ __forceinline__ unsigned short f2bf(float f) {
  union { float f; unsigned int u; } v; v.f = f;
  unsigned int u = v.u;
  u += 0x7fffu + ((u >> 16) & 1u);
  return (unsigned short)(u >> 16);
}
__device__ __forceinline__ unsigned short f2bf_fast(float f) {
  union { float f; unsigned int u; } v; v.f = f;
  return (unsigned short)((v.u + 0x8000u) >> 16);
}

typedef __attribute__((address_space(1))) const unsigned int as1_u32;
typedef __attribute__((address_space(3))) unsigned int as3_u32;
__device__ __forceinline__ void async16(const void* g, void* l) {
  __builtin_amdgcn_global_load_lds((as1_u32*)g, (as3_u32*)l, 16, 0, 0);
}

// ---------------------------------------------------------------------------
// c_qkv GEMM, single-K (K=2048, BK=32 dbuf): writes one fp32 partial buffer P
// (bias added in the LN reduce). Kills the p1 write + read of the split-K
// version (-58 MB HBM round-trip).
// ---------------------------------------------------------------------------
__global__ __launch_bounds__(256) void gemm_dqkv(
    const unsigned short* __restrict__ A,
    const unsigned short* __restrict__ B,
    float* __restrict__ P)
{
  __shared__ __align__(16) unsigned short sm[16384];
  const int tid = threadIdx.x;
  const int w = tid >> 6, lane = tid & 63, q = lane >> 4, r = lane & 15;
  const int bm = blockIdx.y * 128, bn = blockIdx.x * 128;
  const int K = 2048;

  floatx4 acc[4][4];
#pragma unroll
  for (int i = 0; i < 4; i++)
#pragma unroll
    for (int j = 0; j < 4; j++) acc[i][j] = (floatx4){0.f, 0.f, 0.f, 0.f};

  const int srow = tid >> 2, scol = (tid & 3) * 8;
  const unsigned short* Ag0 = A + (size_t)(bm + srow) * 2048 + scol;
  const unsigned short* Ag1 = A + (size_t)(bm + 64 + srow) * 2048 + scol;
  const unsigned short* Bg0 = B + (size_t)(bn + srow) * 2048 + scol;
  const unsigned short* Bg1 = B + (size_t)(bn + 64 + srow) * 2048 + scol;
  const int mrow0 = (w >> 1) * 64, ncol0 = (w & 1) * 64;

  async16(Ag0, &sm[w * 512]);
  async16(Ag1, &sm[2048 + w * 512]);
  async16(Bg0, &sm[8192 + w * 512]);
  async16(Bg1, &sm[8192 + 2048 + w * 512]);

  for (int k0 = 0; k0 < K; k0 += 32) {
    const int cur = (k0 >> 5) & 1;
    __syncthreads();
    if (k0 + 32 < K) {
      const int nxt = cur ^ 1;
      async16(Ag0 + k0 + 32, &sm[nxt * 4096 + w * 512]);
      async16(Ag1 + k0 + 32, &sm[nxt * 4096 + 2048 + w * 512]);
      async16(Bg0 + k0 + 32, &sm[8192 + nxt * 4096 + w * 512]);
      async16(Bg1 + k0 + 32, &sm[8192 + nxt * 4096 + 2048 + w * 512]);
    }
    const unsigned short* As = &sm[cur * 4096];
    const unsigned short* Bs = &sm[8192 + cur * 4096];
    short8 a[4], b[4];
#pragma unroll
    for (int i = 0; i < 4; i++)
      a[i] = *(const short8*)&As[(mrow0 + i * 16 + r) * 32 + q * 8];
#pragma unroll
    for (int j = 0; j < 4; j++)
      b[j] = *(const short8*)&Bs[(ncol0 + j * 16 + r) * 32 + q * 8];
#pragma unroll
    for (int i = 0; i < 4; i++)
#pragma unroll
      for (int j = 0; j < 4; j++)
        acc[i][j] = __builtin_amdgcn_mfma_f32_16x16x32_bf16(a[i], b[j], acc[i][j], 0, 0, 0);
  }

#pragma unroll
  for (int j = 0; j < 4; j++) {
    int gc = bn + ncol0 + j * 16 + r;
#pragma unroll
    for (int i = 0; i < 4; i++) {
#pragma unroll
      for (int v = 0; v < 4; v++) {
        int gr = bm + mrow0 + i * 16 + q * 4 + v;
        P[(size_t)gr * NQKV + gc] = acc[i][j][v];
      }
    }
  }
}

// ---------------------------------------------------------------------------
// Wo GEMM, BK=64 dbuf (unchanged).
// ---------------------------------------------------------------------------
__global__ __launch_bounds__(256) void gemm_wo64(
    const unsigned short* __restrict__ A,
    const unsigned short* __restrict__ B,
    const float* __restrict__ bias, float* __restrict__ C)
{
  __shared__ __align__(16) unsigned short sm[32768]; // A:2x8192 @0, B:@16384
  const int tid = threadIdx.x;
  const int w = tid >> 6, lane = tid & 63, q = lane >> 4, r = lane & 15;
  const int bm = blockIdx.y * 128, bn = blockIdx.x * 128;

  floatx4 acc[4][4];
#pragma unroll
  for (int i = 0; i < 4; i++)
#pragma unroll
    for (int j = 0; j < 4; j++) acc[i][j] = (floatx4){0.f, 0.f, 0.f, 0.f};

  const int srow = tid >> 2, scol = (tid & 3) * 8;
  const unsigned short* Ag0 = A + (size_t)(bm + srow) * 2048 + scol;
  const unsigned short* Ag1 = A + (size_t)(bm + 64 + srow) * 2048 + scol;
  const unsigned short* Bg0 = B + (size_t)(bn + srow) * 2048 + scol;
  const unsigned short* Bg1 = B + (size_t)(bn + 64 + srow) * 2048 + scol;
  const int mrow0 = (w >> 1) * 64, ncol0 = (w & 1) * 64;

#pragma unroll
  for (int c2 = 0; c2 < 2; c2++) {
    async16(Ag0 + c2 * 32, &sm[c2 * 4096 + w * 512]);
    async16(Ag1 + c2 * 32, &sm[c2 * 4096 + 2048 + w * 512]);
    async16(Bg0 + c2 * 32, &sm[16384 + c2 * 4096 + w * 512]);
    async16(Bg1 + c2 * 32, &sm[16384 + c2 * 4096 + 2048 + w * 512]);
  }

  for (int k0 = 0; k0 < 2048; k0 += 64) {
    const int cur = (k0 >> 6) & 1;
    __syncthreads();
    if (k0 + 64 < 2048) {
      const int nxt = cur ^ 1;
#pragma unroll
      for (int c2 = 0; c2 < 2; c2++) {
        async16(Ag0 + k0 + 64 + c2 * 32, &sm[nxt * 8192 + c2 * 4096 + w * 512]);
        async16(Ag1 + k0 + 64 + c2 * 32, &sm[nxt * 8192 + c2 * 4096 + 2048 + w * 512]);
        async16(Bg0 + k0 + 64 + c2 * 32, &sm[16384 + nxt * 8192 + c2 * 4096 + w * 512]);
        async16(Bg1 + k0 + 64 + c2 * 32, &sm[16384 + nxt * 8192 + c2 * 4096 + 2048 + w * 512]);
      }
    }
#pragma unroll
    for (int c2 = 0; c2 < 2; c2++) {
      const unsigned short* As = &sm[cur * 8192 + c2 * 4096];
      const unsigned short* Bs = &sm[16384 + cur * 8192 + c2 * 4096];
      short8 a[4], b[4];
#pragma unroll
      for (int i = 0; i < 4; i++)
        a[i] = *(const short8*)&As[(mrow0 + i * 16 + r) * 32 + q * 8];
#pragma unroll
      for (int j = 0; j < 4; j++)
        b[j] = *(const short8*)&Bs[(ncol0 + j * 16 + r) * 32 + q * 8];
#pragma unroll
      for (int i = 0; i < 4; i++)
#pragma unroll
        for (int j = 0; j < 4; j++)
          acc[i][j] = __builtin_amdgcn_mfma_f32_16x16x32_bf16(a[i], b[j], acc[i][j], 0, 0, 0);
    }
  }

#pragma unroll
  for (int j = 0; j < 4; j++) {
    int gc = bn + ncol0 + j * 16 + r;
    float bv = bias[gc];
#pragma unroll
    for (int i = 0; i < 4; i++) {
#pragma unroll
      for (int v = 0; v < 4; v++) {
        int gr = bm + mrow0 + i * 16 + q * 4 + v;
        C[(size_t)gr * 2048 + gc] = acc[i][j][v] + bv;
      }
    }
  }
}

// ---------------------------------------------------------------------------
// Fused up-projections. Kn/V tile writes in plain block-tile layout (attn
// reads K/V directly from L2 with coalesced wave loads).
// ---------------------------------------------------------------------------
__global__ __launch_bounds__(256) void gemm_up_fused(
    const unsigned short* __restrict__ Aq, const unsigned short* __restrict__ Bq,
    const float* __restrict__ biasq, unsigned short* __restrict__ Qall,
    const unsigned short* __restrict__ Akv, const unsigned short* __restrict__ Bkv,
    const float* __restrict__ biaskv,
    unsigned short* __restrict__ Kn, unsigned short* __restrict__ Vb)
{
  __shared__ __align__(16) unsigned short sm[16384];
  const int tid = threadIdx.x;
  const int w = tid >> 6, lane = tid & 63, q = lane >> 4, r = lane & 15;
  const int bx = blockIdx.x;
  const bool isQ = bx < 16;
  const int bn = isQ ? bx * 128 : (bx - 16) * 128;
  const int bm = blockIdx.y * 128;
  const int K = isQ ? DQP : DKV;
  const unsigned short* A = isQ ? Aq : Akv;
  const unsigned short* B = isQ ? Bq : Bkv;

  floatx4 acc[4][4];
#pragma unroll
  for (int i = 0; i < 4; i++)
#pragma unroll
    for (int j = 0; j < 4; j++) acc[i][j] = (floatx4){0.f, 0.f, 0.f, 0.f};

  const int srow = tid >> 2, scol = (tid & 3) * 8;
  const unsigned short* Ag0 = A + (size_t)(bm + srow) * K + scol;
  const unsigned short* Ag1 = A + (size_t)(bm + 64 + srow) * K + scol;
  const unsigned short* Bg0 = B + (size_t)(bn + srow) * K + scol;
  const unsigned short* Bg1 = B + (size_t)(bn + 64 + srow) * K + scol;
  const int mrow0 = (w >> 1) * 64, ncol0 = (w & 1) * 64;

  async16(Ag0, &sm[w * 512]);
  async16(Ag1, &sm[2048 + w * 512]);
  async16(Bg0, &sm[8192 + w * 512]);
  async16(Bg1, &sm[8192 + 2048 + w * 512]);

  for (int k0 = 0; k0 < K; k0 += 32) {
    const int cur = (k0 >> 5) & 1;
    __syncthreads();
    if (k0 + 32 < K) {
      const int nxt = cur ^ 1;
      async16(Ag0 + k0 + 32, &sm[nxt * 4096 + w * 512]);
      async16(Ag1 + k0 + 32, &sm[nxt * 4096 + 2048 + w * 512]);
      async16(Bg0 + k0 + 32, &sm[8192 + nxt * 4096 + w * 512]);
      async16(Bg1 + k0 + 32, &sm[8192 + nxt * 4096 + 2048 + w * 512]);
    }
    const unsigned short* As = &sm[cur * 4096];
    const unsigned short* Bs = &sm[8192 + cur * 4096];
    short8 a[4], b[4];
#pragma unroll
    for (int i = 0; i < 4; i++)
      a[i] = *(const short8*)&As[(mrow0 + i * 16 + r) * 32 + q * 8];
#pragma unroll
    for (int j = 0; j < 4; j++)
      b[j] = *(const short8*)&Bs[(ncol0 + j * 16 + r) * 32 + q * 8];
#pragma unroll
    for (int i = 0; i < 4; i++)
#pragma unroll
      for (int j = 0; j < 4; j++)
        acc[i][j] = __builtin_amdgcn_mfma_f32_16x16x32_bf16(a[i], b[j], acc[i][j], 0, 0, 0);
  }

  if (!isQ) {
#pragma unroll
    for (int j = 0; j < 4; j++) {
      int gc = bn + ncol0 + j * 16 + r;
      float bv = biaskv[gc];
      int hh = gc / 192;
      int rel = gc - hh * 192;
#pragma unroll
      for (int i = 0; i < 4; i++) {
#pragma unroll
        for (int v = 0; v < 4; v++) {
          int gr = bm + mrow0 + i * 16 + q * 4 + v;
          int bb = gr >> 11, tt = gr & 2047;
          int bhh = bb * NH + hh;
          int kt = tt >> 6;
          unsigned short val = f2bf(acc[i][j][v] + bv);
          if (rel < 64) {
            // K tile: [2 colgrp][64 kv][32 col]
            Kn[((size_t)(bhh * 32 + kt)) * 4096 + (rel >> 5) * 2048 +
               (tt & 63) * 32 + (rel & 31)] = val;
          } else {
            int d = rel - 64;
            // V tile: [2 kvhalf][128 d][32 kv]
            Vb[((size_t)(bhh * 32 + kt)) * 8192 + ((tt >> 5) & 1) * 4096 +
               d * 32 + (tt & 31)] = val;
          }
        }
      }
    }
    return;
  }

  const int h = bx;
  const float QS = (float)(0.08838834764831845 * 1.4426950408889634);
  if ((w & 1) == 0) {
#pragma unroll
    for (int j = 0; j < 4; j++) {
      int d = j * 16 + r;
      float bv = biasq[h * 128 + d];
#pragma unroll
      for (int i = 0; i < 4; i++) {
#pragma unroll
        for (int v = 0; v < 4; v++) {
          int gr = bm + mrow0 + i * 16 + q * 4 + v;
          int bb = gr >> 11, t = gr & 2047;
          Qall[(((size_t)(bb * NH + h)) * T_SEQ + t) * 128 + d] =
              f2bf((acc[i][j][v] + bv) * QS);
        }
      }
    }
  } else {
    float cs[2], sn[2], bv1[2], bv2[2];
#pragma unroll
    for (int jp = 0; jp < 2; jp++) {
      int jj = jp * 16 + r;
      float ang = (float)h * exp2f(-(float)jj * (13.287712379549449f / 32.0f));
      cs[jp] = cosf(ang); sn[jp] = sinf(ang);
      bv1[jp] = biasq[h * 128 + 64 + jj];
      bv2[jp] = biasq[h * 128 + 96 + jj];
    }
#pragma unroll
    for (int i = 0; i < 4; i++) {
#pragma unroll
      for (int v = 0; v < 4; v++) {
        int gr = bm + mrow0 + i * 16 + q * 4 + v;
        int bb = gr >> 11, t = gr & 2047;
        unsigned short* Qr = Qall + (((size_t)(bb * NH + h)) * T_SEQ + t) * 128;
#pragma unroll
        for (int jp = 0; jp < 2; jp++) {
          int jj = jp * 16 + r;
          float x1 = acc[i][jp][v] + bv1[jp];
          float x2 = acc[i][jp + 2][v] + bv2[jp];
          Qr[64 + jj] = f2bf((x1 * cs[jp] + x2 * sn[jp]) * QS);
          Qr[96 + jj] = f2bf((x2 * cs[jp] - x1 * sn[jp]) * QS);
        }
      }
    }
  }
}

// ---------------------------------------------------------------------------
// prep v2: vectorized x4 conversions. Pure-copy regions (icols==ocols) use
// float4 loads + bf16x4 stores; Wdq row-pad handled by a 4-aligned boundary;
// Wuq col-pad (682->704) stays scalar (4 elems/thread).
// ---------------------------------------------------------------------------
__global__ __launch_bounds__(256) void prep_all(
    const float* __restrict__ x,
    const float* __restrict__ Wdq_w, const float* __restrict__ Wdkv_w,
    const float* __restrict__ Wuq_w, const float* __restrict__ Wukv_w,
    const float* __restrict__ Wo_w,
    const float* __restrict__ Wdq_b, const float* __restrict__ Wdkv_b,
    unsigned short* __restrict__ x_bf,
    unsigned short* __restrict__ Wqkv_bf, unsigned short* __restrict__ Wuq_bf,
    unsigned short* __restrict__ Wukv_bf, unsigned short* __restrict__ Wo_bf,
    float* __restrict__ bias_qkv)
{
  const long bx = blockIdx.x;
  const int tid = threadIdx.x;
#define CVT4(inp, outp, i4)                                                    \
  {                                                                            \
    float4 v_ = *(const float4*)&(inp)[i4];                                    \
    ushort4v o_ = {f2bf(v_.x), f2bf(v_.y), f2bf(v_.z), f2bf(v_.w)};            \
    *(ushort4v*)&(outp)[i4] = o_;                                              \
  }
  if (bx < 8192) {                       // x: 4096x2048 pure copy
    long i4 = bx * 1024 + tid * 4;
    CVT4(x, x_bf, i4);
  } else if (bx < 9600) {                // Wdq -> Wqkv rows 0..703 (pad >=682)
    long i4 = (bx - 8192) * 1024 + tid * 4;
    if (i4 < 682L * 2048) {
      CVT4(Wdq_w, Wqkv_bf, i4);
    } else {
      ushort4v z_ = {0, 0, 0, 0};
      *(ushort4v*)&Wqkv_bf[i4] = z_;
    }
  } else if (bx < 11776) {               // Wdkv -> Wqkv rows 704.. pure copy
    long i4 = (bx - 9600) * 1024 + tid * 4;
    float4 v_ = *(const float4*)&Wdkv_w[i4];
    ushort4v o_ = {f2bf(v_.x), f2bf(v_.y), f2bf(v_.z), f2bf(v_.w)};
    *(ushort4v*)&Wqkv_bf[704L * 2048 + i4] = o_;
  } else if (bx < 13184) {               // Wuq: col-pad 682->704, scalar x4
    long i0 = (bx - 11776) * 1024 + tid * 4;
#pragma unroll
    for (int e = 0; e < 4; e++) {
      long idx = i0 + e;
      int rr = (int)(idx / 704);
      int cc = (int)(idx - (long)rr * 704);
      Wuq_bf[idx] = (cc < 682) ? f2bf(Wuq_w[(size_t)rr * 682 + cc]) : 0;
    }
  } else if (bx < 16256) {               // Wukv: 3072x1024 pure copy
    long i4 = (bx - 13184) * 1024 + tid * 4;
    CVT4(Wukv_w, Wukv_bf, i4);
  } else if (bx < 20352) {               // Wo: 2048x2048 pure copy
    long i4 = (bx - 16256) * 1024 + tid * 4;
    CVT4(Wo_w, Wo_bf, i4);
  } else {                               // bias concat
    int i = (int)(bx - 20352) * 256 + tid;
    if (i < NQKV)
      bias_qkv[i] = (i < DQ) ? Wdq_b[i] : ((i < DQP) ? 0.f : Wdkv_b[i - DQP]);
  }
#undef CVT4
}

// ---------------------------------------------------------------------------
// ln_dual_r: single fp32 partial P + bias, dual LayerNorm (single read pass,
// values cached in regs); Kr writes in plain block-tile layout.
// ---------------------------------------------------------------------------
__global__ __launch_bounds__(256) void ln_dual_r(
    const float* __restrict__ p0,
    const float* __restrict__ bqkv,
    unsigned short* __restrict__ outq, unsigned short* __restrict__ outkv,
    unsigned short* __restrict__ Kr,
    const float* __restrict__ qg, const float* __restrict__ qb2,
    const float* __restrict__ kg, const float* __restrict__ kb2)
{
  __shared__ float sbuf[8];
  const int blk = blockIdx.x;
  if (blk >= 8192) {
    const int base = (blk - 8192) * 512;
#pragma unroll
    for (int s = 0; s < 2; s++) {
      int idx = base + s * 256 + threadIdx.x;
      int row = idx >> 6, dr = idx & 63;
      size_t off = (size_t)row * NQKV + 1728 + dr;
      float v = p0[off] + bqkv[1728 + dr];
      Kr[((size_t)((row >> 11) * 32 + ((row & 2047) >> 6))) * 4096 +
         (dr >> 5) * 2048 + (row & 63) * 32 + (dr & 31)] = f2bf(v);
    }
    return;
  }
  const bool isQ = blk < 4096;
  const int r2 = isQ ? blk : blk - 4096;
  const int off = isQ ? 0 : DQP;
  const float* x0 = p0 + (size_t)r2 * NQKV + off;
  const float* bb = bqkv + off;
  const int D = isQ ? DQ : DKV;
  const int ocols = isQ ? DQP : DKV;
  const float* g = isQ ? qg : kg;
  const float* bta = isQ ? qb2 : kb2;
  unsigned short* orow = (isQ ? outq : outkv) + (size_t)r2 * ocols;

  float s = 0.f, s2 = 0.f;
  float vv[4];
#pragma unroll
  for (int ii = 0; ii < 4; ii++) {
    int i = threadIdx.x + ii * 256;
    if (i < D) {
      float v = x0[i] + bb[i];
      vv[ii] = v;
      s += v; s2 += v * v;
    }
  }
#pragma unroll
  for (int o = 32; o > 0; o >>= 1) {
    s += __shfl_down(s, o, 64);
    s2 += __shfl_down(s2, o, 64);
  }
  int wid = threadIdx.x >> 6;
  __syncthreads();
  if ((threadIdx.x & 63) == 0) { sbuf[wid] = s; sbuf[4 + wid] = s2; }
  __syncthreads();
  float su = sbuf[0] + sbuf[1] + sbuf[2] + sbuf[3];
  float sq = sbuf[4] + sbuf[5] + sbuf[6] + sbuf[7];
  float mu = su / (float)D;
  float var = sq / (float)D - mu * mu;
  float rstd = rsqrtf(var + 1e-5f);
#pragma unroll
  for (int ii = 0; ii < 4; ii++) {
    int i = threadIdx.x + ii * 256;
    if (i < ocols)
      orow[i] = (i < D) ? f2bf((vv[ii] - mu) * rstd * g[i] + bta[i]) : 0;
  }
}

// ---------------------------------------------------------------------------
// attn v10: 1024 blocks x 128 threads (2 waves), one 64-row q-tile each,
// barrier-free v9 body (L2-direct K/V, wave-private Psw). With <=128 VGPR
// (launch_bounds(128,4)) and 4.6KB LDS, 4 blocks = 8 waves fit on EVERY CU
// for the whole kernel — no light/heavy temporal segregation (the v4-v9
// occupancy hole). Tile order: s=id>>5, x=s&7, quadrants give
// a in {31-x, 23-x, x+8, x} -> under stride-256 placement each CU's 4 blocks
// sum to exactly 66 iterations; heavy quadrant dispatched first.
// bh = id&31 keeps id%8==bh%8 (XCD L2 affinity for K/V).
// ---------------------------------------------------------------------------
__global__ __launch_bounds__(128, 4) void attn_mfma10(
    const unsigned short* __restrict__ Qall,
    const unsigned short* __restrict__ Kn,
    const unsigned short* __restrict__ Kr,
    const unsigned short* __restrict__ Vb,
    unsigned short* __restrict__ y)
{
  __shared__ __align__(16) unsigned short Pswb[2304];  // 2 waves x 1152 shorts
  const int id = (int)blockIdx.x;
  const int bhid = id & 31;
  const int s = id >> 5;                 // 0..31
  const int xx = s & 7, quad = s >> 3;
  const int a = (quad == 0) ? (31 - xx) : (quad == 1) ? (23 - xx)
              : (quad == 2) ? (xx + 8) : xx;   // q-tile: rows [a*64, a*64+64)
  const int h = bhid & 15, b = bhid >> 4;
  const int tid = threadIdx.x;
  const int w = tid >> 6, lane = tid & 63, q = lane >> 4, r = lane & 15;
  const int bh = bhid;

  const unsigned short* KnT0 = Kn + (size_t)bh * 131072;   // 32kt x 4096
  const unsigned short* KrT0 = Kr + (size_t)b * 131072;
  const unsigned short* VT0  = Vb + (size_t)bh * 262144;   // 32kt x 8192
  unsigned short* Psw = Pswb + w * 1152;

  // Q fragments: rows a*64 + w*32 + g*16 + r
  short8 qb[2][4];
#pragma unroll
  for (int g = 0; g < 2; g++) {
    const unsigned short* Qrow =
        Qall + ((size_t)bh * T_SEQ + (size_t)a * 64 + w * 32 + g * 16 + r) * 128 + q * 8;
#pragma unroll
    for (int c = 0; c < 4; c++) qb[g][c] = *(const short8*)(Qrow + c * 32);
  }

  floatx4 oacc[2][8];
#pragma unroll
  for (int g = 0; g < 2; g++)
#pragma unroll
    for (int jd = 0; jd < 8; jd++) oacc[g][jd] = (floatx4){0.f, 0.f, 0.f, 0.f};
  float m_i[2] = {-3.0e38f, -3.0e38f}, l_i[2] = {0.f, 0.f};

  for (int kt = 0; kt <= a; kt++) {
    const unsigned short* KnT = KnT0 + kt * 4096;
    const unsigned short* KrT = KrT0 + kt * 4096;
    const unsigned short* VT  = VT0 + kt * 8192;

    // K fragments straight from L2 (coalesced 1KB per wave-load)
    floatx4 sacc[2][4];
#pragma unroll
    for (int g = 0; g < 2; g++)
#pragma unroll
      for (int j = 0; j < 4; j++) sacc[g][j] = (floatx4){0.f, 0.f, 0.f, 0.f};
    {
      short8 ak[4][4];
#pragma unroll
      for (int c = 0; c < 4; c++) {
        const unsigned short* Ksrc = (c < 2) ? (KnT + c * 2048) : (KrT + (c - 2) * 2048);
#pragma unroll
        for (int j = 0; j < 4; j++)
          ak[c][j] = *(const short8*)&Ksrc[(j * 16 + r) * 32 + q * 8];
      }
      __builtin_amdgcn_s_setprio(1);
#pragma unroll
      for (int c = 0; c < 4; c++)
#pragma unroll
        for (int g = 0; g < 2; g++)
#pragma unroll
          for (int j = 0; j < 4; j++)
            sacc[g][j] = __builtin_amdgcn_mfma_f32_16x16x32_bf16(ak[c][j], qb[g][c], sacc[g][j], 0, 0, 0);
      __builtin_amdgcn_s_setprio(0);
    }

    // V fragment loads issued now — L2 latency hides under softmax
    short8 vb[2][8];
#pragma unroll
    for (int c2 = 0; c2 < 2; c2++)
#pragma unroll
      for (int jd = 0; jd < 8; jd++)
        vb[c2][jd] = *(const short8*)&VT[c2 * 4096 + (jd * 16 + r) * 32 + q * 8];

    short8 pb[2][2];
#pragma unroll
    for (int g = 0; g < 2; g++) {
      float sv[16];
#pragma unroll
      for (int j = 0; j < 4; j++)
#pragma unroll
        for (int v = 0; v < 4; v++) sv[j * 4 + v] = sacc[g][j][v];
      const int rel = a * 64 + w * 32 + g * 16 + r - kt * 64;
      if (rel < 63) {
#pragma unroll
        for (int j = 0; j < 4; j++)
#pragma unroll
          for (int v = 0; v < 4; v++)
            if (j * 16 + q * 4 + v > rel) sv[j * 4 + v] = -3.0e38f;
      }
      // tree-reduce max
      float tm[8];
#pragma unroll
      for (int t = 0; t < 8; t++) tm[t] = fmaxf(sv[t], sv[t + 8]);
#pragma unroll
      for (int t = 0; t < 4; t++) tm[t] = fmaxf(tm[t], tm[t + 4]);
      float rm = fmaxf(fmaxf(tm[0], tm[2]), fmaxf(tm[1], tm[3]));
      rm = fmaxf(rm, __shfl_xor(rm, 16, 64));
      rm = fmaxf(rm, __shfl_xor(rm, 32, 64));
      // defer-max: rescale only if tile max grew > 8 (log2 units)
      if (__any(rm > m_i[g] + 8.f)) {
        float mnew = fmaxf(m_i[g], rm);
        float alpha = exp2f(m_i[g] - mnew);
        m_i[g] = mnew;
        l_i[g] *= alpha;
#pragma unroll
        for (int jd = 0; jd < 8; jd++) {
          oacc[g][jd][0] *= alpha; oacc[g][jd][1] *= alpha;
          oacc[g][jd][2] *= alpha; oacc[g][jd][3] *= alpha;
        }
      }
      float p[16];
#pragma unroll
      for (int t = 0; t < 16; t++) p[t] = exp2f(sv[t] - m_i[g]);
      float ts[8];
#pragma unroll
      for (int t = 0; t < 8; t++) ts[t] = p[t] + p[t + 8];
#pragma unroll
      for (int t = 0; t < 4; t++) ts[t] = ts[t] + ts[t + 4];
      float rsum = (ts[0] + ts[2]) + (ts[1] + ts[3]);
      rsum += __shfl_xor(rsum, 16, 64);
      rsum += __shfl_xor(rsum, 32, 64);
      l_i[g] += rsum;
#pragma unroll
      for (int j = 0; j < 4; j++) {
        unsigned int lo = (unsigned int)f2bf_fast(p[j * 4 + 0]) |
                          ((unsigned int)f2bf_fast(p[j * 4 + 1]) << 16);
        unsigned int hi = (unsigned int)f2bf_fast(p[j * 4 + 2]) |
                          ((unsigned int)f2bf_fast(p[j * 4 + 3]) << 16);
        uint2v pk; pk[0] = lo; pk[1] = hi;
        *(uint2v*)&Psw[r * 72 + j * 16 + q * 4] = pk;
      }
      pb[g][0] = *(const short8*)&Psw[r * 72 + q * 8];
      pb[g][1] = *(const short8*)&Psw[r * 72 + 32 + q * 8];
    }

    // PV: each V fragment feeds both row-groups
    __builtin_amdgcn_s_setprio(1);
#pragma unroll
    for (int c2 = 0; c2 < 2; c2++) {
#pragma unroll
      for (int jd = 0; jd < 8; jd++) {
        oacc[0][jd] = __builtin_amdgcn_mfma_f32_16x16x32_bf16(vb[c2][jd], pb[0][c2], oacc[0][jd], 0, 0, 0);
        oacc[1][jd] = __builtin_amdgcn_mfma_f32_16x16x32_bf16(vb[c2][jd], pb[1][c2], oacc[1][jd], 0, 0, 0);
      }
    }
    __builtin_amdgcn_s_setprio(0);
  }

#pragma unroll
  for (int g = 0; g < 2; g++) {
    float inv = 1.0f / l_i[g];
    unsigned short* yr =
        y + ((size_t)(b * T_SEQ) + (size_t)a * 64 + w * 32 + g * 16 + r) * DM + h * 128;
#pragma unroll
    for (int jd = 0; jd < 8; jd++) {
      unsigned short o0 = f2bf(oacc[g][jd][0] * inv);
      unsigned short o1 = f2bf(oacc[g][jd][1] * inv);
      unsigned short o2 = f2bf(oacc[g][jd][2] * inv);
      unsigned short o3 = f2bf(oacc[g][jd][3] * inv);
      unsigned int lo = (unsigned int)o0 | ((unsigned int)o1 << 16);
      unsigned int hi = (unsigned int)o2 | ((unsigned int)o3 << 16);
      unsigned int* dst = (unsigned int*)(yr + jd * 16 + q * 4);
      dst[0] = lo; dst[1] = hi;
    }
  }
}

// ---------------------------------------------------------------------------
extern "C" void kernel_launch(void* const* d_in, const int* in_sizes, int n_in,
                              void* d_out, int out_size, void* d_ws, size_t ws_size,
                              hipStream_t stream) {
  const float* x      = (const float*)d_in[0];
  const float* Wdq_w  = (const float*)d_in[1];
  const float* Wdq_b  = (const float*)d_in[2];
  const float* qn_g   = (const float*)d_in[3];
  const float* qn_b   = (const float*)d_in[4];
  const float* Wuq_w  = (const float*)d_in[5];
  const float* Wuq_b  = (const float*)d_in[6];
  const float* Wdkv_w = (const float*)d_in[7];
  const float* Wdkv_b = (const float*)d_in[8];
  const float* kvn_g  = (const float*)d_in[9];
  const float* kvn_b  = (const float*)d_in[10];
  const float* Wukv_w = (const float*)d_in[11];
  const float* Wukv_b = (const float*)d_in[12];
  const float* Wo_w   = (const float*)d_in[13];
  const float* Wo_b   = (const float*)d_in[14];
  float* out = (float*)d_out;

  float* ws = (float*)d_ws;
  unsigned short* x_bf    = (unsigned short*)(ws);              // dies after dqkv gemm
  unsigned short* y_bf    = (unsigned short*)(ws);              // alias: attn output
  unsigned short* Wqkv_bf = (unsigned short*)(ws + 4194304);    // 1792x2048
  unsigned short* Wuq_bf  = (unsigned short*)(ws + 6029312);    // 2048x704
  unsigned short* Wukv_bf = (unsigned short*)(ws + 6750208);    // 3072x1024
  float* bias_qkv = ws + 8323072;                               // 1792
  float* p0       = ws + 8324864;                               // 4096x1792 fp32
  unsigned short* c_q_bf = (unsigned short*)(ws + 23004928);    // 4096x704
  unsigned short* kvn_bf = (unsigned short*)(ws + 24446720);    // 4096x1024
  unsigned short* Q_all  = (unsigned short*)(ws + 26543872);    // 2x16x2048x128
  unsigned short* Kn_blk = (unsigned short*)(ws + 30738176);    // 32bh x 32kt x 4096
  unsigned short* Kr_blk = (unsigned short*)(ws + 32835328);    // 2b x 32kt x 4096
  unsigned short* V_blk  = (unsigned short*)(ws + 32966400);    // 32bh x 32kt x 8192
  unsigned short* Wo_bf  = (unsigned short*)(ws + 37160704);    // 2048x2048

  dim3 blk(256);

  // one prep launch: x cvt + weights + bias concat (vectorized x4)
  prep_all<<<20359, blk, 0, stream>>>(x, Wdq_w, Wdkv_w, Wuq_w, Wukv_w, Wo_w,
                                      Wdq_b, Wdkv_b,
                                      x_bf, Wqkv_bf, Wuq_bf, Wukv_bf, Wo_bf,
                                      bias_qkv);
  // c_qkv partials (single-K, 448 blocks)
  gemm_dqkv<<<dim3(14, 32), blk, 0, stream>>>(x_bf, Wqkv_bf, p0);
  // reduce + dual LN + rope->Kr_blk
  ln_dual_r<<<8704, blk, 0, stream>>>(p0, bias_qkv, c_q_bf, kvn_bf, Kr_blk,
                                      qn_g, qn_b, kvn_g, kvn_b);
  // fused up-projections: qrope -> Q_all ; kv -> Kn_blk / V_blk
  gemm_up_fused<<<dim3(40, 32), blk, 0, stream>>>(c_q_bf, Wuq_bf, Wuq_b, Q_all,
                                                  kvn_bf, Wukv_bf, Wukv_b,
                                                  Kn_blk, V_blk);
  // attention: 1024x128, all blocks co-resident, balanced quadrant order
  attn_mfma10<<<1024, dim3(128), 0, stream>>>(Q_all, Kn_blk, Kr_blk, V_blk, y_bf);
  // out = y @ Wo^T + b (BK=64 dbuf)
  gemm_wo64<<<dim3(16, 32), blk, 0, stream>>>(y_bf, Wo_bf, Wo_b, out);
}

// Round 7
// 391.643 us; speedup vs baseline: 2.0178x; 2.0178x over previous
//
#include <hip/hip_runtime.h>
#include <math.h>

#define TOK 4096
#define DM 2048
#define DQ 682
#define DQP 704
#define DKV 1024
#define DUKV 3072
#define NH 16
#define T_SEQ 2048
#define NQKV 1792   // 704 (padded Wdq) + 1088 (Wdkv)

typedef __attribute__((ext_vector_type(8))) short short8;
typedef __attribute__((ext_vector_type(4))) float floatx4;
typedef __attribute__((ext_vector_type(4))) unsigned short ushort4v;
typedef __attribute__((ext_vector_type(2))) unsigned int uint2v;

__device__ __forceinline__ unsigned short f2bf(float f) {
  union { float f; unsigned int u; } v; v.f = f;
  unsigned int u = v.u;
  u += 0x7fffu + ((u >> 16) & 1u);
  return (unsigned short)(u >> 16);
}
__device__ __forceinline__ unsigned short f2bf_fast(float f) {
  union { float f; unsigned int u; } v; v.f = f;
  return (unsigned short)((v.u + 0x8000u) >> 16);
}

typedef __attribute__((address_space(1))) const unsigned int as1_u32;
typedef __attribute__((address_space(3))) unsigned int as3_u32;
__device__ __forceinline__ void async16(const void* g, void* l) {
  __builtin_amdgcn_global_load_lds((as1_u32*)g, (as3_u32*)l, 16, 0, 0);
}

// ---------------------------------------------------------------------------
// c_qkv GEMM, single-K (K=2048, BK=32 dbuf): writes one fp32 partial buffer P
// (bias added in the LN reduce).
// ---------------------------------------------------------------------------
__global__ __launch_bounds__(256) void gemm_dqkv(
    const unsigned short* __restrict__ A,
    const unsigned short* __restrict__ B,
    float* __restrict__ P)
{
  __shared__ __align__(16) unsigned short sm[16384];
  const int tid = threadIdx.x;
  const int w = tid >> 6, lane = tid & 63, q = lane >> 4, r = lane & 15;
  const int bm = blockIdx.y * 128, bn = blockIdx.x * 128;
  const int K = 2048;

  floatx4 acc[4][4];
#pragma unroll
  for (int i = 0; i < 4; i++)
#pragma unroll
    for (int j = 0; j < 4; j++) acc[i][j] = (floatx4){0.f, 0.f, 0.f, 0.f};

  const int srow = tid >> 2, scol = (tid & 3) * 8;
  const unsigned short* Ag0 = A + (size_t)(bm + srow) * 2048 + scol;
  const unsigned short* Ag1 = A + (size_t)(bm + 64 + srow) * 2048 + scol;
  const unsigned short* Bg0 = B + (size_t)(bn + srow) * 2048 + scol;
  const unsigned short* Bg1 = B + (size_t)(bn + 64 + srow) * 2048 + scol;
  const int mrow0 = (w >> 1) * 64, ncol0 = (w & 1) * 64;

  async16(Ag0, &sm[w * 512]);
  async16(Ag1, &sm[2048 + w * 512]);
  async16(Bg0, &sm[8192 + w * 512]);
  async16(Bg1, &sm[8192 + 2048 + w * 512]);

  for (int k0 = 0; k0 < K; k0 += 32) {
    const int cur = (k0 >> 5) & 1;
    __syncthreads();
    if (k0 + 32 < K) {
      const int nxt = cur ^ 1;
      async16(Ag0 + k0 + 32, &sm[nxt * 4096 + w * 512]);
      async16(Ag1 + k0 + 32, &sm[nxt * 4096 + 2048 + w * 512]);
      async16(Bg0 + k0 + 32, &sm[8192 + nxt * 4096 + w * 512]);
      async16(Bg1 + k0 + 32, &sm[8192 + nxt * 4096 + 2048 + w * 512]);
    }
    const unsigned short* As = &sm[cur * 4096];
    const unsigned short* Bs = &sm[8192 + cur * 4096];
    short8 a[4], b[4];
#pragma unroll
    for (int i = 0; i < 4; i++)
      a[i] = *(const short8*)&As[(mrow0 + i * 16 + r) * 32 + q * 8];
#pragma unroll
    for (int j = 0; j < 4; j++)
      b[j] = *(const short8*)&Bs[(ncol0 + j * 16 + r) * 32 + q * 8];
#pragma unroll
    for (int i = 0; i < 4; i++)
#pragma unroll
      for (int j = 0; j < 4; j++)
        acc[i][j] = __builtin_amdgcn_mfma_f32_16x16x32_bf16(a[i], b[j], acc[i][j], 0, 0, 0);
  }

#pragma unroll
  for (int j = 0; j < 4; j++) {
    int gc = bn + ncol0 + j * 16 + r;
#pragma unroll
    for (int i = 0; i < 4; i++) {
#pragma unroll
      for (int v = 0; v < 4; v++) {
        int gr = bm + mrow0 + i * 16 + q * 4 + v;
        P[(size_t)gr * NQKV + gc] = acc[i][j][v];
      }
    }
  }
}

// ---------------------------------------------------------------------------
// Wo GEMM, BK=64 dbuf (unchanged).
// ---------------------------------------------------------------------------
__global__ __launch_bounds__(256) void gemm_wo64(
    const unsigned short* __restrict__ A,
    const unsigned short* __restrict__ B,
    const float* __restrict__ bias, float* __restrict__ C)
{
  __shared__ __align__(16) unsigned short sm[32768]; // A:2x8192 @0, B:@16384
  const int tid = threadIdx.x;
  const int w = tid >> 6, lane = tid & 63, q = lane >> 4, r = lane & 15;
  const int bm = blockIdx.y * 128, bn = blockIdx.x * 128;

  floatx4 acc[4][4];
#pragma unroll
  for (int i = 0; i < 4; i++)
#pragma unroll
    for (int j = 0; j < 4; j++) acc[i][j] = (floatx4){0.f, 0.f, 0.f, 0.f};

  const int srow = tid >> 2, scol = (tid & 3) * 8;
  const unsigned short* Ag0 = A + (size_t)(bm + srow) * 2048 + scol;
  const unsigned short* Ag1 = A + (size_t)(bm + 64 + srow) * 2048 + scol;
  const unsigned short* Bg0 = B + (size_t)(bn + srow) * 2048 + scol;
  const unsigned short* Bg1 = B + (size_t)(bn + 64 + srow) * 2048 + scol;
  const int mrow0 = (w >> 1) * 64, ncol0 = (w & 1) * 64;

#pragma unroll
  for (int c2 = 0; c2 < 2; c2++) {
    async16(Ag0 + c2 * 32, &sm[c2 * 4096 + w * 512]);
    async16(Ag1 + c2 * 32, &sm[c2 * 4096 + 2048 + w * 512]);
    async16(Bg0 + c2 * 32, &sm[16384 + c2 * 4096 + w * 512]);
    async16(Bg1 + c2 * 32, &sm[16384 + c2 * 4096 + 2048 + w * 512]);
  }

  for (int k0 = 0; k0 < 2048; k0 += 64) {
    const int cur = (k0 >> 6) & 1;
    __syncthreads();
    if (k0 + 64 < 2048) {
      const int nxt = cur ^ 1;
#pragma unroll
      for (int c2 = 0; c2 < 2; c2++) {
        async16(Ag0 + k0 + 64 + c2 * 32, &sm[nxt * 8192 + c2 * 4096 + w * 512]);
        async16(Ag1 + k0 + 64 + c2 * 32, &sm[nxt * 8192 + c2 * 4096 + 2048 + w * 512]);
        async16(Bg0 + k0 + 64 + c2 * 32, &sm[16384 + nxt * 8192 + c2 * 4096 + w * 512]);
        async16(Bg1 + k0 + 64 + c2 * 32, &sm[16384 + nxt * 8192 + c2 * 4096 + 2048 + w * 512]);
      }
    }
#pragma unroll
    for (int c2 = 0; c2 < 2; c2++) {
      const unsigned short* As = &sm[cur * 8192 + c2 * 4096];
      const unsigned short* Bs = &sm[16384 + cur * 8192 + c2 * 4096];
      short8 a[4], b[4];
#pragma unroll
      for (int i = 0; i < 4; i++)
        a[i] = *(const short8*)&As[(mrow0 + i * 16 + r) * 32 + q * 8];
#pragma unroll
      for (int j = 0; j < 4; j++)
        b[j] = *(const short8*)&Bs[(ncol0 + j * 16 + r) * 32 + q * 8];
#pragma unroll
      for (int i = 0; i < 4; i++)
#pragma unroll
        for (int j = 0; j < 4; j++)
          acc[i][j] = __builtin_amdgcn_mfma_f32_16x16x32_bf16(a[i], b[j], acc[i][j], 0, 0, 0);
    }
  }

#pragma unroll
  for (int j = 0; j < 4; j++) {
    int gc = bn + ncol0 + j * 16 + r;
    float bv = bias[gc];
#pragma unroll
    for (int i = 0; i < 4; i++) {
#pragma unroll
      for (int v = 0; v < 4; v++) {
        int gr = bm + mrow0 + i * 16 + q * 4 + v;
        C[(size_t)gr * 2048 + gc] = acc[i][j][v] + bv;
      }
    }
  }
}

// ---------------------------------------------------------------------------
// Fused up-projections. Kn/V tile writes in plain block-tile layout (attn
// reads K/V directly from L2 with coalesced wave loads).
// ---------------------------------------------------------------------------
__global__ __launch_bounds__(256) void gemm_up_fused(
    const unsigned short* __restrict__ Aq, const unsigned short* __restrict__ Bq,
    const float* __restrict__ biasq, unsigned short* __restrict__ Qall,
    const unsigned short* __restrict__ Akv, const unsigned short* __restrict__ Bkv,
    const float* __restrict__ biaskv,
    unsigned short* __restrict__ Kn, unsigned short* __restrict__ Vb)
{
  __shared__ __align__(16) unsigned short sm[16384];
  const int tid = threadIdx.x;
  const int w = tid >> 6, lane = tid & 63, q = lane >> 4, r = lane & 15;
  const int bx = blockIdx.x;
  const bool isQ = bx < 16;
  const int bn = isQ ? bx * 128 : (bx - 16) * 128;
  const int bm = blockIdx.y * 128;
  const int K = isQ ? DQP : DKV;
  const unsigned short* A = isQ ? Aq : Akv;
  const unsigned short* B = isQ ? Bq : Bkv;

  floatx4 acc[4][4];
#pragma unroll
  for (int i = 0; i < 4; i++)
#pragma unroll
    for (int j = 0; j < 4; j++) acc[i][j] = (floatx4){0.f, 0.f, 0.f, 0.f};

  const int srow = tid >> 2, scol = (tid & 3) * 8;
  const unsigned short* Ag0 = A + (size_t)(bm + srow) * K + scol;
  const unsigned short* Ag1 = A + (size_t)(bm + 64 + srow) * K + scol;
  const unsigned short* Bg0 = B + (size_t)(bn + srow) * K + scol;
  const unsigned short* Bg1 = B + (size_t)(bn + 64 + srow) * K + scol;
  const int mrow0 = (w >> 1) * 64, ncol0 = (w & 1) * 64;

  async16(Ag0, &sm[w * 512]);
  async16(Ag1, &sm[2048 + w * 512]);
  async16(Bg0, &sm[8192 + w * 512]);
  async16(Bg1, &sm[8192 + 2048 + w * 512]);

  for (int k0 = 0; k0 < K; k0 += 32) {
    const int cur = (k0 >> 5) & 1;
    __syncthreads();
    if (k0 + 32 < K) {
      const int nxt = cur ^ 1;
      async16(Ag0 + k0 + 32, &sm[nxt * 4096 + w * 512]);
      async16(Ag1 + k0 + 32, &sm[nxt * 4096 + 2048 + w * 512]);
      async16(Bg0 + k0 + 32, &sm[8192 + nxt * 4096 + w * 512]);
      async16(Bg1 + k0 + 32, &sm[8192 + nxt * 4096 + 2048 + w * 512]);
    }
    const unsigned short* As = &sm[cur * 4096];
    const unsigned short* Bs = &sm[8192 + cur * 4096];
    short8 a[4], b[4];
#pragma unroll
    for (int i = 0; i < 4; i++)
      a[i] = *(const short8*)&As[(mrow0 + i * 16 + r) * 32 + q * 8];
#pragma unroll
    for (int j = 0; j < 4; j++)
      b[j] = *(const short8*)&Bs[(ncol0 + j * 16 + r) * 32 + q * 8];
#pragma unroll
    for (int i = 0; i < 4; i++)
#pragma unroll
      for (int j = 0; j < 4; j++)
        acc[i][j] = __builtin_amdgcn_mfma_f32_16x16x32_bf16(a[i], b[j], acc[i][j], 0, 0, 0);
  }

  if (!isQ) {
#pragma unroll
    for (int j = 0; j < 4; j++) {
      int gc = bn + ncol0 + j * 16 + r;
      float bv = biaskv[gc];
      int hh = gc / 192;
      int rel = gc - hh * 192;
#pragma unroll
      for (int i = 0; i < 4; i++) {
#pragma unroll
        for (int v = 0; v < 4; v++) {
          int gr = bm + mrow0 + i * 16 + q * 4 + v;
          int bb = gr >> 11, tt = gr & 2047;
          int bhh = bb * NH + hh;
          int kt = tt >> 6;
          unsigned short val = f2bf(acc[i][j][v] + bv);
          if (rel < 64) {
            // K tile: [2 colgrp][64 kv][32 col]
            Kn[((size_t)(bhh * 32 + kt)) * 4096 + (rel >> 5) * 2048 +
               (tt & 63) * 32 + (rel & 31)] = val;
          } else {
            int d = rel - 64;
            // V tile: [2 kvhalf][128 d][32 kv]
            Vb[((size_t)(bhh * 32 + kt)) * 8192 + ((tt >> 5) & 1) * 4096 +
               d * 32 + (tt & 31)] = val;
          }
        }
      }
    }
    return;
  }

  const int h = bx;
  const float QS = (float)(0.08838834764831845 * 1.4426950408889634);
  if ((w & 1) == 0) {
#pragma unroll
    for (int j = 0; j < 4; j++) {
      int d = j * 16 + r;
      float bv = biasq[h * 128 + d];
#pragma unroll
      for (int i = 0; i < 4; i++) {
#pragma unroll
        for (int v = 0; v < 4; v++) {
          int gr = bm + mrow0 + i * 16 + q * 4 + v;
          int bb = gr >> 11, t = gr & 2047;
          Qall[(((size_t)(bb * NH + h)) * T_SEQ + t) * 128 + d] =
              f2bf((acc[i][j][v] + bv) * QS);
        }
      }
    }
  } else {
    float cs[2], sn[2], bv1[2], bv2[2];
#pragma unroll
    for (int jp = 0; jp < 2; jp++) {
      int jj = jp * 16 + r;
      float ang = (float)h * exp2f(-(float)jj * (13.287712379549449f / 32.0f));
      cs[jp] = cosf(ang); sn[jp] = sinf(ang);
      bv1[jp] = biasq[h * 128 + 64 + jj];
      bv2[jp] = biasq[h * 128 + 96 + jj];
    }
#pragma unroll
    for (int i = 0; i < 4; i++) {
#pragma unroll
      for (int v = 0; v < 4; v++) {
        int gr = bm + mrow0 + i * 16 + q * 4 + v;
        int bb = gr >> 11, t = gr & 2047;
        unsigned short* Qr = Qall + (((size_t)(bb * NH + h)) * T_SEQ + t) * 128;
#pragma unroll
        for (int jp = 0; jp < 2; jp++) {
          int jj = jp * 16 + r;
          float x1 = acc[i][jp][v] + bv1[jp];
          float x2 = acc[i][jp + 2][v] + bv2[jp];
          Qr[64 + jj] = f2bf((x1 * cs[jp] + x2 * sn[jp]) * QS);
          Qr[96 + jj] = f2bf((x2 * cs[jp] - x1 * sn[jp]) * QS);
        }
      }
    }
  }
}

// ---------------------------------------------------------------------------
// prep v2: vectorized x4 conversions (unchanged from round 6 — confirmed win).
// ---------------------------------------------------------------------------
__global__ __launch_bounds__(256) void prep_all(
    const float* __restrict__ x,
    const float* __restrict__ Wdq_w, const float* __restrict__ Wdkv_w,
    const float* __restrict__ Wuq_w, const float* __restrict__ Wukv_w,
    const float* __restrict__ Wo_w,
    const float* __restrict__ Wdq_b, const float* __restrict__ Wdkv_b,
    unsigned short* __restrict__ x_bf,
    unsigned short* __restrict__ Wqkv_bf, unsigned short* __restrict__ Wuq_bf,
    unsigned short* __restrict__ Wukv_bf, unsigned short* __restrict__ Wo_bf,
    float* __restrict__ bias_qkv)
{
  const long bx = blockIdx.x;
  const int tid = threadIdx.x;
#define CVT4(inp, outp, i4)                                                    \
  {                                                                            \
    float4 v_ = *(const float4*)&(inp)[i4];                                    \
    ushort4v o_ = {f2bf(v_.x), f2bf(v_.y), f2bf(v_.z), f2bf(v_.w)};            \
    *(ushort4v*)&(outp)[i4] = o_;                                              \
  }
  if (bx < 8192) {                       // x: 4096x2048 pure copy
    long i4 = bx * 1024 + tid * 4;
    CVT4(x, x_bf, i4);
  } else if (bx < 9600) {                // Wdq -> Wqkv rows 0..703 (pad >=682)
    long i4 = (bx - 8192) * 1024 + tid * 4;
    if (i4 < 682L * 2048) {
      CVT4(Wdq_w, Wqkv_bf, i4);
    } else {
      ushort4v z_ = {0, 0, 0, 0};
      *(ushort4v*)&Wqkv_bf[i4] = z_;
    }
  } else if (bx < 11776) {               // Wdkv -> Wqkv rows 704.. pure copy
    long i4 = (bx - 9600) * 1024 + tid * 4;
    float4 v_ = *(const float4*)&Wdkv_w[i4];
    ushort4v o_ = {f2bf(v_.x), f2bf(v_.y), f2bf(v_.z), f2bf(v_.w)};
    *(ushort4v*)&Wqkv_bf[704L * 2048 + i4] = o_;
  } else if (bx < 13184) {               // Wuq: col-pad 682->704, scalar x4
    long i0 = (bx - 11776) * 1024 + tid * 4;
#pragma unroll
    for (int e = 0; e < 4; e++) {
      long idx = i0 + e;
      int rr = (int)(idx / 704);
      int cc = (int)(idx - (long)rr * 704);
      Wuq_bf[idx] = (cc < 682) ? f2bf(Wuq_w[(size_t)rr * 682 + cc]) : 0;
    }
  } else if (bx < 16256) {               // Wukv: 3072x1024 pure copy
    long i4 = (bx - 13184) * 1024 + tid * 4;
    CVT4(Wukv_w, Wukv_bf, i4);
  } else if (bx < 20352) {               // Wo: 2048x2048 pure copy
    long i4 = (bx - 16256) * 1024 + tid * 4;
    CVT4(Wo_w, Wo_bf, i4);
  } else {                               // bias concat
    int i = (int)(bx - 20352) * 256 + tid;
    if (i < NQKV)
      bias_qkv[i] = (i < DQ) ? Wdq_b[i] : ((i < DQP) ? 0.f : Wdkv_b[i - DQP]);
  }
#undef CVT4
}

// ---------------------------------------------------------------------------
// ln_dual_r: single fp32 partial P + bias, dual LayerNorm (single read pass);
// Kr writes in plain block-tile layout.
// ---------------------------------------------------------------------------
__global__ __launch_bounds__(256) void ln_dual_r(
    const float* __restrict__ p0,
    const float* __restrict__ bqkv,
    unsigned short* __restrict__ outq, unsigned short* __restrict__ outkv,
    unsigned short* __restrict__ Kr,
    const float* __restrict__ qg, const float* __restrict__ qb2,
    const float* __restrict__ kg, const float* __restrict__ kb2)
{
  __shared__ float sbuf[8];
  const int blk = blockIdx.x;
  if (blk >= 8192) {
    const int base = (blk - 8192) * 512;
#pragma unroll
    for (int s = 0; s < 2; s++) {
      int idx = base + s * 256 + threadIdx.x;
      int row = idx >> 6, dr = idx & 63;
      size_t off = (size_t)row * NQKV + 1728 + dr;
      float v = p0[off] + bqkv[1728 + dr];
      Kr[((size_t)((row >> 11) * 32 + ((row & 2047) >> 6))) * 4096 +
         (dr >> 5) * 2048 + (row & 63) * 32 + (dr & 31)] = f2bf(v);
    }
    return;
  }
  const bool isQ = blk < 4096;
  const int r2 = isQ ? blk : blk - 4096;
  const int off = isQ ? 0 : DQP;
  const float* x0 = p0 + (size_t)r2 * NQKV + off;
  const float* bb = bqkv + off;
  const int D = isQ ? DQ : DKV;
  const int ocols = isQ ? DQP : DKV;
  const float* g = isQ ? qg : kg;
  const float* bta = isQ ? qb2 : kb2;
  unsigned short* orow = (isQ ? outq : outkv) + (size_t)r2 * ocols;

  float s = 0.f, s2 = 0.f;
  float vv[4];
#pragma unroll
  for (int ii = 0; ii < 4; ii++) {
    int i = threadIdx.x + ii * 256;
    if (i < D) {
      float v = x0[i] + bb[i];
      vv[ii] = v;
      s += v; s2 += v * v;
    }
  }
#pragma unroll
  for (int o = 32; o > 0; o >>= 1) {
    s += __shfl_down(s, o, 64);
    s2 += __shfl_down(s2, o, 64);
  }
  int wid = threadIdx.x >> 6;
  __syncthreads();
  if ((threadIdx.x & 63) == 0) { sbuf[wid] = s; sbuf[4 + wid] = s2; }
  __syncthreads();
  float su = sbuf[0] + sbuf[1] + sbuf[2] + sbuf[3];
  float sq = sbuf[4] + sbuf[5] + sbuf[6] + sbuf[7];
  float mu = su / (float)D;
  float var = sq / (float)D - mu * mu;
  float rstd = rsqrtf(var + 1e-5f);
#pragma unroll
  for (int ii = 0; ii < 4; ii++) {
    int i = threadIdx.x + ii * 256;
    if (i < ocols)
      orow[i] = (i < D) ? f2bf((vv[ii] - mu) * rstd * g[i] + bta[i]) : 0;
  }
}

// ---------------------------------------------------------------------------
// attn v11 = v10 schedule with the VGPR spill fixed. 1024 blocks x 128
// threads (2 waves), one 64-row q-tile each, barrier-free L2-direct body
// (identical per-wave code to v9, which compiled to 124 VGPR).
// __launch_bounds__(128, 2) caps at 256 VGPR -> no spill; 4 blocks/CU
// co-resident = 8 waves sustained for the whole kernel. Quadrant tile order
// {31-x, 23-x, x+8, x}: each CU's four blocks sum to exactly 66 iterations.
// bh = id&31 keeps id%8==bh%8 (XCD L2 affinity).
// ---------------------------------------------------------------------------
__global__ __launch_bounds__(128, 2) void attn_mfma11(
    const unsigned short* __restrict__ Qall,
    const unsigned short* __restrict__ Kn,
    const unsigned short* __restrict__ Kr,
    const unsigned short* __restrict__ Vb,
    unsigned short* __restrict__ y)
{
  __shared__ __align__(16) unsigned short Pswb[2304];  // 2 waves x 1152 shorts
  const int id = (int)blockIdx.x;
  const int bhid = id & 31;
  const int s = id >> 5;                 // 0..31
  const int xx = s & 7, quad = s >> 3;
  const int a = (quad == 0) ? (31 - xx) : (quad == 1) ? (23 - xx)
              : (quad == 2) ? (xx + 8) : xx;   // q-tile: rows [a*64, a*64+64)
  const int h = bhid & 15, b = bhid >> 4;
  const int tid = threadIdx.x;
  const int w = tid >> 6, lane = tid & 63, q = lane >> 4, r = lane & 15;
  const int bh = bhid;

  const unsigned short* KnT0 = Kn + (size_t)bh * 131072;   // 32kt x 4096
  const unsigned short* KrT0 = Kr + (size_t)b * 131072;
  const unsigned short* VT0  = Vb + (size_t)bh * 262144;   // 32kt x 8192
  unsigned short* Psw = Pswb + w * 1152;

  // Q fragments: rows a*64 + w*32 + g*16 + r
  short8 qb[2][4];
#pragma unroll
  for (int g = 0; g < 2; g++) {
    const unsigned short* Qrow =
        Qall + ((size_t)bh * T_SEQ + (size_t)a * 64 + w * 32 + g * 16 + r) * 128 + q * 8;
#pragma unroll
    for (int c = 0; c < 4; c++) qb[g][c] = *(const short8*)(Qrow + c * 32);
  }

  floatx4 oacc[2][8];
#pragma unroll
  for (int g = 0; g < 2; g++)
#pragma unroll
    for (int jd = 0; jd < 8; jd++) oacc[g][jd] = (floatx4){0.f, 0.f, 0.f, 0.f};
  float m_i[2] = {-3.0e38f, -3.0e38f}, l_i[2] = {0.f, 0.f};

  for (int kt = 0; kt <= a; kt++) {
    const unsigned short* KnT = KnT0 + kt * 4096;
    const unsigned short* KrT = KrT0 + kt * 4096;
    const unsigned short* VT  = VT0 + kt * 8192;

    // K fragments straight from L2 (coalesced 1KB per wave-load)
    floatx4 sacc[2][4];
#pragma unroll
    for (int g = 0; g < 2; g++)
#pragma unroll
      for (int j = 0; j < 4; j++) sacc[g][j] = (floatx4){0.f, 0.f, 0.f, 0.f};
    {
      short8 ak[4][4];
#pragma unroll
      for (int c = 0; c < 4; c++) {
        const unsigned short* Ksrc = (c < 2) ? (KnT + c * 2048) : (KrT + (c - 2) * 2048);
#pragma unroll
        for (int j = 0; j < 4; j++)
          ak[c][j] = *(const short8*)&Ksrc[(j * 16 + r) * 32 + q * 8];
      }
      __builtin_amdgcn_s_setprio(1);
#pragma unroll
      for (int c = 0; c < 4; c++)
#pragma unroll
        for (int g = 0; g < 2; g++)
#pragma unroll
          for (int j = 0; j < 4; j++)
            sacc[g][j] = __builtin_amdgcn_mfma_f32_16x16x32_bf16(ak[c][j], qb[g][c], sacc[g][j], 0, 0, 0);
      __builtin_amdgcn_s_setprio(0);
    }

    // V fragment loads issued now — L2 latency hides under softmax
    short8 vb[2][8];
#pragma unroll
    for (int c2 = 0; c2 < 2; c2++)
#pragma unroll
      for (int jd = 0; jd < 8; jd++)
        vb[c2][jd] = *(const short8*)&VT[c2 * 4096 + (jd * 16 + r) * 32 + q * 8];

    short8 pb[2][2];
#pragma unroll
    for (int g = 0; g < 2; g++) {
      float sv[16];
#pragma unroll
      for (int j = 0; j < 4; j++)
#pragma unroll
        for (int v = 0; v < 4; v++) sv[j * 4 + v] = sacc[g][j][v];
      const int rel = a * 64 + w * 32 + g * 16 + r - kt * 64;
      if (rel < 63) {
#pragma unroll
        for (int j = 0; j < 4; j++)
#pragma unroll
          for (int v = 0; v < 4; v++)
            if (j * 16 + q * 4 + v > rel) sv[j * 4 + v] = -3.0e38f;
      }
      // tree-reduce max
      float tm[8];
#pragma unroll
      for (int t = 0; t < 8; t++) tm[t] = fmaxf(sv[t], sv[t + 8]);
#pragma unroll
      for (int t = 0; t < 4; t++) tm[t] = fmaxf(tm[t], tm[t + 4]);
      float rm = fmaxf(fmaxf(tm[0], tm[2]), fmaxf(tm[1], tm[3]));
      rm = fmaxf(rm, __shfl_xor(rm, 16, 64));
      rm = fmaxf(rm, __shfl_xor(rm, 32, 64));
      // defer-max: rescale only if tile max grew > 8 (log2 units)
      if (__any(rm > m_i[g] + 8.f)) {
        float mnew = fmaxf(m_i[g], rm);
        float alpha = exp2f(m_i[g] - mnew);
        m_i[g] = mnew;
        l_i[g] *= alpha;
#pragma unroll
        for (int jd = 0; jd < 8; jd++) {
          oacc[g][jd][0] *= alpha; oacc[g][jd][1] *= alpha;
          oacc[g][jd][2] *= alpha; oacc[g][jd][3] *= alpha;
        }
      }
      float p[16];
#pragma unroll
      for (int t = 0; t < 16; t++) p[t] = exp2f(sv[t] - m_i[g]);
      float ts[8];
#pragma unroll
      for (int t = 0; t < 8; t++) ts[t] = p[t] + p[t + 8];
#pragma unroll
      for (int t = 0; t < 4; t++) ts[t] = ts[t] + ts[t + 4];
      float rsum = (ts[0] + ts[2]) + (ts[1] + ts[3]);
      rsum += __shfl_xor(rsum, 16, 64);
      rsum += __shfl_xor(rsum, 32, 64);
      l_i[g] += rsum;
#pragma unroll
      for (int j = 0; j < 4; j++) {
        unsigned int lo = (unsigned int)f2bf_fast(p[j * 4 + 0]) |
                          ((unsigned int)f2bf_fast(p[j * 4 + 1]) << 16);
        unsigned int hi = (unsigned int)f2bf_fast(p[j * 4 + 2]) |
                          ((unsigned int)f2bf_fast(p[j * 4 + 3]) << 16);
        uint2v pk; pk[0] = lo; pk[1] = hi;
        *(uint2v*)&Psw[r * 72 + j * 16 + q * 4] = pk;
      }
      pb[g][0] = *(const short8*)&Psw[r * 72 + q * 8];
      pb[g][1] = *(const short8*)&Psw[r * 72 + 32 + q * 8];
    }

    // PV: each V fragment feeds both row-groups
    __builtin_amdgcn_s_setprio(1);
#pragma unroll
    for (int c2 = 0; c2 < 2; c2++) {
#pragma unroll
      for (int jd = 0; jd < 8; jd++) {
        oacc[0][jd] = __builtin_amdgcn_mfma_f32_16x16x32_bf16(vb[c2][jd], pb[0][c2], oacc[0][jd], 0, 0, 0);
        oacc[1][jd] = __builtin_amdgcn_mfma_f32_16x16x32_bf16(vb[c2][jd], pb[1][c2], oacc[1][jd], 0, 0, 0);
      }
    }
    __builtin_amdgcn_s_setprio(0);
  }

#pragma unroll
  for (int g = 0; g < 2; g++) {
    float inv = 1.0f / l_i[g];
    unsigned short* yr =
        y + ((size_t)(b * T_SEQ) + (size_t)a * 64 + w * 32 + g * 16 + r) * DM + h * 128;
#pragma unroll
    for (int jd = 0; jd < 8; jd++) {
      unsigned short o0 = f2bf(oacc[g][jd][0] * inv);
      unsigned short o1 = f2bf(oacc[g][jd][1] * inv);
      unsigned short o2 = f2bf(oacc[g][jd][2] * inv);
      unsigned short o3 = f2bf(oacc[g][jd][3] * inv);
      unsigned int lo = (unsigned int)o0 | ((unsigned int)o1 << 16);
      unsigned int hi = (unsigned int)o2 | ((unsigned int)o3 << 16);
      unsigned int* dst = (unsigned int*)(yr + jd * 16 + q * 4);
      dst[0] = lo; dst[1] = hi;
    }
  }
}

// ---------------------------------------------------------------------------
extern "C" void kernel_launch(void* const* d_in, const int* in_sizes, int n_in,
                              void* d_out, int out_size, void* d_ws, size_t ws_size,
                              hipStream_t stream) {
  const float* x      = (const float*)d_in[0];
  const float* Wdq_w  = (const float*)d_in[1];
  const float* Wdq_b  = (const float*)d_in[2];
  const float* qn_g   = (const float*)d_in[3];
  const float* qn_b   = (const float*)d_in[4];
  const float* Wuq_w  = (const float*)d_in[5];
  const float* Wuq_b  = (const float*)d_in[6];
  const float* Wdkv_w = (const float*)d_in[7];
  const float* Wdkv_b = (const float*)d_in[8];
  const float* kvn_g  = (const float*)d_in[9];
  const float* kvn_b  = (const float*)d_in[10];
  const float* Wukv_w = (const float*)d_in[11];
  const float* Wukv_b = (const float*)d_in[12];
  const float* Wo_w   = (const float*)d_in[13];
  const float* Wo_b   = (const float*)d_in[14];
  float* out = (float*)d_out;

  float* ws = (float*)d_ws;
  unsigned short* x_bf    = (unsigned short*)(ws);              // dies after dqkv gemm
  unsigned short* y_bf    = (unsigned short*)(ws);              // alias: attn output
  unsigned short* Wqkv_bf = (unsigned short*)(ws + 4194304);    // 1792x2048
  unsigned short* Wuq_bf  = (unsigned short*)(ws + 6029312);    // 2048x704
  unsigned short* Wukv_bf = (unsigned short*)(ws + 6750208);    // 3072x1024
  float* bias_qkv = ws + 8323072;                               // 1792
  float* p0       = ws + 8324864;                               // 4096x1792 fp32
  unsigned short* c_q_bf = (unsigned short*)(ws + 23004928);    // 4096x704
  unsigned short* kvn_bf = (unsigned short*)(ws + 24446720);    // 4096x1024
  unsigned short* Q_all  = (unsigned short*)(ws + 26543872);    // 2x16x2048x128
  unsigned short* Kn_blk = (unsigned short*)(ws + 30738176);    // 32bh x 32kt x 4096
  unsigned short* Kr_blk = (unsigned short*)(ws + 32835328);    // 2b x 32kt x 4096
  unsigned short* V_blk  = (unsigned short*)(ws + 32966400);    // 32bh x 32kt x 8192
  unsigned short* Wo_bf  = (unsigned short*)(ws + 37160704);    // 2048x2048

  dim3 blk(256);

  // one prep launch: x cvt + weights + bias concat (vectorized x4)
  prep_all<<<20359, blk, 0, stream>>>(x, Wdq_w, Wdkv_w, Wuq_w, Wukv_w, Wo_w,
                                      Wdq_b, Wdkv_b,
                                      x_bf, Wqkv_bf, Wuq_bf, Wukv_bf, Wo_bf,
                                      bias_qkv);
  // c_qkv partials (single-K, 448 blocks)
  gemm_dqkv<<<dim3(14, 32), blk, 0, stream>>>(x_bf, Wqkv_bf, p0);
  // reduce + dual LN + rope->Kr_blk
  ln_dual_r<<<8704, blk, 0, stream>>>(p0, bias_qkv, c_q_bf, kvn_bf, Kr_blk,
                                      qn_g, qn_b, kvn_g, kvn_b);
  // fused up-projections: qrope -> Q_all ; kv -> Kn_blk / V_blk
  gemm_up_fused<<<dim3(40, 32), blk, 0, stream>>>(c_q_bf, Wuq_bf, Wuq_b, Q_all,
                                                  kvn_bf, Wukv_bf, Wukv_b,
                                                  Kn_blk, V_blk);
  // attention: 1024x128, 4 blocks/CU sustained, balanced quadrant order
  attn_mfma11<<<1024, dim3(128), 0, stream>>>(Q_all, Kn_blk, Kr_blk, V_blk, y_bf);
  // out = y @ Wo^T + b (BK=64 dbuf)
  gemm_wo64<<<dim3(16, 32), blk, 0, stream>>>(y_bf, Wo_bf, Wo_b, out);
}

// Round 8
// 390.196 us; speedup vs baseline: 2.0253x; 1.0037x over previous
//
#include <hip/hip_runtime.h>
#include <math.h>

#define TOK 4096
#define DM 2048
#define DQ 682
#define DQP 704
#define DKV 1024
#define DUKV 3072
#define NH 16
#define T_SEQ 2048
#define NQKV 1792   // 704 (padded Wdq) + 1088 (Wdkv)

typedef __attribute__((ext_vector_type(8))) short short8;
typedef __attribute__((ext_vector_type(4))) float floatx4;
typedef __attribute__((ext_vector_type(4))) unsigned short ushort4v;
typedef __attribute__((ext_vector_type(2))) unsigned int uint2v;

__device__ __forceinline__ unsigned short f2bf(float f) {
  union { float f; unsigned int u; } v; v.f = f;
  unsigned int u = v.u;
  u += 0x7fffu + ((u >> 16) & 1u);
  return (unsigned short)(u >> 16);
}
__device__ __forceinline__ unsigned short f2bf_fast(float f) {
  union { float f; unsigned int u; } v; v.f = f;
  return (unsigned short)((v.u + 0x8000u) >> 16);
}

typedef __attribute__((address_space(1))) const unsigned int as1_u32;
typedef __attribute__((address_space(3))) unsigned int as3_u32;
__device__ __forceinline__ void async16(const void* g, void* l) {
  __builtin_amdgcn_global_load_lds((as1_u32*)g, (as3_u32*)l, 16, 0, 0);
}

// ---------------------------------------------------------------------------
// c_qkv GEMM, single-K (K=2048, BK=32 dbuf): writes one fp32 partial buffer P
// (bias added in the LN reduce).
// ---------------------------------------------------------------------------
__global__ __launch_bounds__(256) void gemm_dqkv(
    const unsigned short* __restrict__ A,
    const unsigned short* __restrict__ B,
    float* __restrict__ P)
{
  __shared__ __align__(16) unsigned short sm[16384];
  const int tid = threadIdx.x;
  const int w = tid >> 6, lane = tid & 63, q = lane >> 4, r = lane & 15;
  const int bm = blockIdx.y * 128, bn = blockIdx.x * 128;
  const int K = 2048;

  floatx4 acc[4][4];
#pragma unroll
  for (int i = 0; i < 4; i++)
#pragma unroll
    for (int j = 0; j < 4; j++) acc[i][j] = (floatx4){0.f, 0.f, 0.f, 0.f};

  const int srow = tid >> 2, scol = (tid & 3) * 8;
  const unsigned short* Ag0 = A + (size_t)(bm + srow) * 2048 + scol;
  const unsigned short* Ag1 = A + (size_t)(bm + 64 + srow) * 2048 + scol;
  const unsigned short* Bg0 = B + (size_t)(bn + srow) * 2048 + scol;
  const unsigned short* Bg1 = B + (size_t)(bn + 64 + srow) * 2048 + scol;
  const int mrow0 = (w >> 1) * 64, ncol0 = (w & 1) * 64;

  async16(Ag0, &sm[w * 512]);
  async16(Ag1, &sm[2048 + w * 512]);
  async16(Bg0, &sm[8192 + w * 512]);
  async16(Bg1, &sm[8192 + 2048 + w * 512]);

  for (int k0 = 0; k0 < K; k0 += 32) {
    const int cur = (k0 >> 5) & 1;
    __syncthreads();
    if (k0 + 32 < K) {
      const int nxt = cur ^ 1;
      async16(Ag0 + k0 + 32, &sm[nxt * 4096 + w * 512]);
      async16(Ag1 + k0 + 32, &sm[nxt * 4096 + 2048 + w * 512]);
      async16(Bg0 + k0 + 32, &sm[8192 + nxt * 4096 + w * 512]);
      async16(Bg1 + k0 + 32, &sm[8192 + nxt * 4096 + 2048 + w * 512]);
    }
    const unsigned short* As = &sm[cur * 4096];
    const unsigned short* Bs = &sm[8192 + cur * 4096];
    short8 a[4], b[4];
#pragma unroll
    for (int i = 0; i < 4; i++)
      a[i] = *(const short8*)&As[(mrow0 + i * 16 + r) * 32 + q * 8];
#pragma unroll
    for (int j = 0; j < 4; j++)
      b[j] = *(const short8*)&Bs[(ncol0 + j * 16 + r) * 32 + q * 8];
#pragma unroll
    for (int i = 0; i < 4; i++)
#pragma unroll
      for (int j = 0; j < 4; j++)
        acc[i][j] = __builtin_amdgcn_mfma_f32_16x16x32_bf16(a[i], b[j], acc[i][j], 0, 0, 0);
  }

#pragma unroll
  for (int j = 0; j < 4; j++) {
    int gc = bn + ncol0 + j * 16 + r;
#pragma unroll
    for (int i = 0; i < 4; i++) {
#pragma unroll
      for (int v = 0; v < 4; v++) {
        int gr = bm + mrow0 + i * 16 + q * 4 + v;
        P[(size_t)gr * NQKV + gc] = acc[i][j][v];
      }
    }
  }
}

// ---------------------------------------------------------------------------
// Wo GEMM, BK=64 dbuf (unchanged).
// ---------------------------------------------------------------------------
__global__ __launch_bounds__(256) void gemm_wo64(
    const unsigned short* __restrict__ A,
    const unsigned short* __restrict__ B,
    const float* __restrict__ bias, float* __restrict__ C)
{
  __shared__ __align__(16) unsigned short sm[32768]; // A:2x8192 @0, B:@16384
  const int tid = threadIdx.x;
  const int w = tid >> 6, lane = tid & 63, q = lane >> 4, r = lane & 15;
  const int bm = blockIdx.y * 128, bn = blockIdx.x * 128;

  floatx4 acc[4][4];
#pragma unroll
  for (int i = 0; i < 4; i++)
#pragma unroll
    for (int j = 0; j < 4; j++) acc[i][j] = (floatx4){0.f, 0.f, 0.f, 0.f};

  const int srow = tid >> 2, scol = (tid & 3) * 8;
  const unsigned short* Ag0 = A + (size_t)(bm + srow) * 2048 + scol;
  const unsigned short* Ag1 = A + (size_t)(bm + 64 + srow) * 2048 + scol;
  const unsigned short* Bg0 = B + (size_t)(bn + srow) * 2048 + scol;
  const unsigned short* Bg1 = B + (size_t)(bn + 64 + srow) * 2048 + scol;
  const int mrow0 = (w >> 1) * 64, ncol0 = (w & 1) * 64;

#pragma unroll
  for (int c2 = 0; c2 < 2; c2++) {
    async16(Ag0 + c2 * 32, &sm[c2 * 4096 + w * 512]);
    async16(Ag1 + c2 * 32, &sm[c2 * 4096 + 2048 + w * 512]);
    async16(Bg0 + c2 * 32, &sm[16384 + c2 * 4096 + w * 512]);
    async16(Bg1 + c2 * 32, &sm[16384 + c2 * 4096 + 2048 + w * 512]);
  }

  for (int k0 = 0; k0 < 2048; k0 += 64) {
    const int cur = (k0 >> 6) & 1;
    __syncthreads();
    if (k0 + 64 < 2048) {
      const int nxt = cur ^ 1;
#pragma unroll
      for (int c2 = 0; c2 < 2; c2++) {
        async16(Ag0 + k0 + 64 + c2 * 32, &sm[nxt * 8192 + c2 * 4096 + w * 512]);
        async16(Ag1 + k0 + 64 + c2 * 32, &sm[nxt * 8192 + c2 * 4096 + 2048 + w * 512]);
        async16(Bg0 + k0 + 64 + c2 * 32, &sm[16384 + nxt * 8192 + c2 * 4096 + w * 512]);
        async16(Bg1 + k0 + 64 + c2 * 32, &sm[16384 + nxt * 8192 + c2 * 4096 + 2048 + w * 512]);
      }
    }
#pragma unroll
    for (int c2 = 0; c2 < 2; c2++) {
      const unsigned short* As = &sm[cur * 8192 + c2 * 4096];
      const unsigned short* Bs = &sm[16384 + cur * 8192 + c2 * 4096];
      short8 a[4], b[4];
#pragma unroll
      for (int i = 0; i < 4; i++)
        a[i] = *(const short8*)&As[(mrow0 + i * 16 + r) * 32 + q * 8];
#pragma unroll
      for (int j = 0; j < 4; j++)
        b[j] = *(const short8*)&Bs[(ncol0 + j * 16 + r) * 32 + q * 8];
#pragma unroll
      for (int i = 0; i < 4; i++)
#pragma unroll
        for (int j = 0; j < 4; j++)
          acc[i][j] = __builtin_amdgcn_mfma_f32_16x16x32_bf16(a[i], b[j], acc[i][j], 0, 0, 0);
    }
  }

#pragma unroll
  for (int j = 0; j < 4; j++) {
    int gc = bn + ncol0 + j * 16 + r;
    float bv = bias[gc];
#pragma unroll
    for (int i = 0; i < 4; i++) {
#pragma unroll
      for (int v = 0; v < 4; v++) {
        int gr = bm + mrow0 + i * 16 + q * 4 + v;
        C[(size_t)gr * 2048 + gc] = acc[i][j][v] + bv;
      }
    }
  }
}

// ---------------------------------------------------------------------------
// Fused up-projections. Kn/V tile writes in plain block-tile layout.
// ---------------------------------------------------------------------------
__global__ __launch_bounds__(256) void gemm_up_fused(
    const unsigned short* __restrict__ Aq, const unsigned short* __restrict__ Bq,
    const float* __restrict__ biasq, unsigned short* __restrict__ Qall,
    const unsigned short* __restrict__ Akv, const unsigned short* __restrict__ Bkv,
    const float* __restrict__ biaskv,
    unsigned short* __restrict__ Kn, unsigned short* __restrict__ Vb)
{
  __shared__ __align__(16) unsigned short sm[16384];
  const int tid = threadIdx.x;
  const int w = tid >> 6, lane = tid & 63, q = lane >> 4, r = lane & 15;
  const int bx = blockIdx.x;
  const bool isQ = bx < 16;
  const int bn = isQ ? bx * 128 : (bx - 16) * 128;
  const int bm = blockIdx.y * 128;
  const int K = isQ ? DQP : DKV;
  const unsigned short* A = isQ ? Aq : Akv;
  const unsigned short* B = isQ ? Bq : Bkv;

  floatx4 acc[4][4];
#pragma unroll
  for (int i = 0; i < 4; i++)
#pragma unroll
    for (int j = 0; j < 4; j++) acc[i][j] = (floatx4){0.f, 0.f, 0.f, 0.f};

  const int srow = tid >> 2, scol = (tid & 3) * 8;
  const unsigned short* Ag0 = A + (size_t)(bm + srow) * K + scol;
  const unsigned short* Ag1 = A + (size_t)(bm + 64 + srow) * K + scol;
  const unsigned short* Bg0 = B + (size_t)(bn + srow) * K + scol;
  const unsigned short* Bg1 = B + (size_t)(bn + 64 + srow) * K + scol;
  const int mrow0 = (w >> 1) * 64, ncol0 = (w & 1) * 64;

  async16(Ag0, &sm[w * 512]);
  async16(Ag1, &sm[2048 + w * 512]);
  async16(Bg0, &sm[8192 + w * 512]);
  async16(Bg1, &sm[8192 + 2048 + w * 512]);

  for (int k0 = 0; k0 < K; k0 += 32) {
    const int cur = (k0 >> 5) & 1;
    __syncthreads();
    if (k0 + 32 < K) {
      const int nxt = cur ^ 1;
      async16(Ag0 + k0 + 32, &sm[nxt * 4096 + w * 512]);
      async16(Ag1 + k0 + 32, &sm[nxt * 4096 + 2048 + w * 512]);
      async16(Bg0 + k0 + 32, &sm[8192 + nxt * 4096 + w * 512]);
      async16(Bg1 + k0 + 32, &sm[8192 + nxt * 4096 + 2048 + w * 512]);
    }
    const unsigned short* As = &sm[cur * 4096];
    const unsigned short* Bs = &sm[8192 + cur * 4096];
    short8 a[4], b[4];
#pragma unroll
    for (int i = 0; i < 4; i++)
      a[i] = *(const short8*)&As[(mrow0 + i * 16 + r) * 32 + q * 8];
#pragma unroll
    for (int j = 0; j < 4; j++)
      b[j] = *(const short8*)&Bs[(ncol0 + j * 16 + r) * 32 + q * 8];
#pragma unroll
    for (int i = 0; i < 4; i++)
#pragma unroll
      for (int j = 0; j < 4; j++)
        acc[i][j] = __builtin_amdgcn_mfma_f32_16x16x32_bf16(a[i], b[j], acc[i][j], 0, 0, 0);
  }

  if (!isQ) {
#pragma unroll
    for (int j = 0; j < 4; j++) {
      int gc = bn + ncol0 + j * 16 + r;
      float bv = biaskv[gc];
      int hh = gc / 192;
      int rel = gc - hh * 192;
#pragma unroll
      for (int i = 0; i < 4; i++) {
#pragma unroll
        for (int v = 0; v < 4; v++) {
          int gr = bm + mrow0 + i * 16 + q * 4 + v;
          int bb = gr >> 11, tt = gr & 2047;
          int bhh = bb * NH + hh;
          int kt = tt >> 6;
          unsigned short val = f2bf(acc[i][j][v] + bv);
          if (rel < 64) {
            Kn[((size_t)(bhh * 32 + kt)) * 4096 + (rel >> 5) * 2048 +
               (tt & 63) * 32 + (rel & 31)] = val;
          } else {
            int d = rel - 64;
            Vb[((size_t)(bhh * 32 + kt)) * 8192 + ((tt >> 5) & 1) * 4096 +
               d * 32 + (tt & 31)] = val;
          }
        }
      }
    }
    return;
  }

  const int h = bx;
  const float QS = (float)(0.08838834764831845 * 1.4426950408889634);
  if ((w & 1) == 0) {
#pragma unroll
    for (int j = 0; j < 4; j++) {
      int d = j * 16 + r;
      float bv = biasq[h * 128 + d];
#pragma unroll
      for (int i = 0; i < 4; i++) {
#pragma unroll
        for (int v = 0; v < 4; v++) {
          int gr = bm + mrow0 + i * 16 + q * 4 + v;
          int bb = gr >> 11, t = gr & 2047;
          Qall[(((size_t)(bb * NH + h)) * T_SEQ + t) * 128 + d] =
              f2bf((acc[i][j][v] + bv) * QS);
        }
      }
    }
  } else {
    float cs[2], sn[2], bv1[2], bv2[2];
#pragma unroll
    for (int jp = 0; jp < 2; jp++) {
      int jj = jp * 16 + r;
      float ang = (float)h * exp2f(-(float)jj * (13.287712379549449f / 32.0f));
      cs[jp] = cosf(ang); sn[jp] = sinf(ang);
      bv1[jp] = biasq[h * 128 + 64 + jj];
      bv2[jp] = biasq[h * 128 + 96 + jj];
    }
#pragma unroll
    for (int i = 0; i < 4; i++) {
#pragma unroll
      for (int v = 0; v < 4; v++) {
        int gr = bm + mrow0 + i * 16 + q * 4 + v;
        int bb = gr >> 11, t = gr & 2047;
        unsigned short* Qr = Qall + (((size_t)(bb * NH + h)) * T_SEQ + t) * 128;
#pragma unroll
        for (int jp = 0; jp < 2; jp++) {
          int jj = jp * 16 + r;
          float x1 = acc[i][jp][v] + bv1[jp];
          float x2 = acc[i][jp + 2][v] + bv2[jp];
          Qr[64 + jj] = f2bf((x1 * cs[jp] + x2 * sn[jp]) * QS);
          Qr[96 + jj] = f2bf((x2 * cs[jp] - x1 * sn[jp]) * QS);
        }
      }
    }
  }
}

// ---------------------------------------------------------------------------
// prep v2: vectorized x4 conversions.
// ---------------------------------------------------------------------------
__global__ __launch_bounds__(256) void prep_all(
    const float* __restrict__ x,
    const float* __restrict__ Wdq_w, const float* __restrict__ Wdkv_w,
    const float* __restrict__ Wuq_w, const float* __restrict__ Wukv_w,
    const float* __restrict__ Wo_w,
    const float* __restrict__ Wdq_b, const float* __restrict__ Wdkv_b,
    unsigned short* __restrict__ x_bf,
    unsigned short* __restrict__ Wqkv_bf, unsigned short* __restrict__ Wuq_bf,
    unsigned short* __restrict__ Wukv_bf, unsigned short* __restrict__ Wo_bf,
    float* __restrict__ bias_qkv)
{
  const long bx = blockIdx.x;
  const int tid = threadIdx.x;
#define CVT4(inp, outp, i4)                                                    \
  {                                                                            \
    float4 v_ = *(const float4*)&(inp)[i4];                                    \
    ushort4v o_ = {f2bf(v_.x), f2bf(v_.y), f2bf(v_.z), f2bf(v_.w)};            \
    *(ushort4v*)&(outp)[i4] = o_;                                              \
  }
  if (bx < 8192) {
    long i4 = bx * 1024 + tid * 4;
    CVT4(x, x_bf, i4);
  } else if (bx < 9600) {
    long i4 = (bx - 8192) * 1024 + tid * 4;
    if (i4 < 682L * 2048) {
      CVT4(Wdq_w, Wqkv_bf, i4);
    } else {
      ushort4v z_ = {0, 0, 0, 0};
      *(ushort4v*)&Wqkv_bf[i4] = z_;
    }
  } else if (bx < 11776) {
    long i4 = (bx - 9600) * 1024 + tid * 4;
    float4 v_ = *(const float4*)&Wdkv_w[i4];
    ushort4v o_ = {f2bf(v_.x), f2bf(v_.y), f2bf(v_.z), f2bf(v_.w)};
    *(ushort4v*)&Wqkv_bf[704L * 2048 + i4] = o_;
  } else if (bx < 13184) {
    long i0 = (bx - 11776) * 1024 + tid * 4;
#pragma unroll
    for (int e = 0; e < 4; e++) {
      long idx = i0 + e;
      int rr = (int)(idx / 704);
      int cc = (int)(idx - (long)rr * 704);
      Wuq_bf[idx] = (cc < 682) ? f2bf(Wuq_w[(size_t)rr * 682 + cc]) : 0;
    }
  } else if (bx < 16256) {
    long i4 = (bx - 13184) * 1024 + tid * 4;
    CVT4(Wukv_w, Wukv_bf, i4);
  } else if (bx < 20352) {
    long i4 = (bx - 16256) * 1024 + tid * 4;
    CVT4(Wo_w, Wo_bf, i4);
  } else {
    int i = (int)(bx - 20352) * 256 + tid;
    if (i < NQKV)
      bias_qkv[i] = (i < DQ) ? Wdq_b[i] : ((i < DQP) ? 0.f : Wdkv_b[i - DQP]);
  }
#undef CVT4
}

// ---------------------------------------------------------------------------
// ln_dual_r: single fp32 partial P + bias, dual LayerNorm (single read pass);
// Kr writes in plain block-tile layout.
// ---------------------------------------------------------------------------
__global__ __launch_bounds__(256) void ln_dual_r(
    const float* __restrict__ p0,
    const float* __restrict__ bqkv,
    unsigned short* __restrict__ outq, unsigned short* __restrict__ outkv,
    unsigned short* __restrict__ Kr,
    const float* __restrict__ qg, const float* __restrict__ qb2,
    const float* __restrict__ kg, const float* __restrict__ kb2)
{
  __shared__ float sbuf[8];
  const int blk = blockIdx.x;
  if (blk >= 8192) {
    const int base = (blk - 8192) * 512;
#pragma unroll
    for (int s = 0; s < 2; s++) {
      int idx = base + s * 256 + threadIdx.x;
      int row = idx >> 6, dr = idx & 63;
      size_t off = (size_t)row * NQKV + 1728 + dr;
      float v = p0[off] + bqkv[1728 + dr];
      Kr[((size_t)((row >> 11) * 32 + ((row & 2047) >> 6))) * 4096 +
         (dr >> 5) * 2048 + (row & 63) * 32 + (dr & 31)] = f2bf(v);
    }
    return;
  }
  const bool isQ = blk < 4096;
  const int r2 = isQ ? blk : blk - 4096;
  const int off = isQ ? 0 : DQP;
  const float* x0 = p0 + (size_t)r2 * NQKV + off;
  const float* bb = bqkv + off;
  const int D = isQ ? DQ : DKV;
  const int ocols = isQ ? DQP : DKV;
  const float* g = isQ ? qg : kg;
  const float* bta = isQ ? qb2 : kb2;
  unsigned short* orow = (isQ ? outq : outkv) + (size_t)r2 * ocols;

  float s = 0.f, s2 = 0.f;
  float vv[4];
#pragma unroll
  for (int ii = 0; ii < 4; ii++) {
    int i = threadIdx.x + ii * 256;
    if (i < D) {
      float v = x0[i] + bb[i];
      vv[ii] = v;
      s += v; s2 += v * v;
    }
  }
#pragma unroll
  for (int o = 32; o > 0; o >>= 1) {
    s += __shfl_down(s, o, 64);
    s2 += __shfl_down(s2, o, 64);
  }
  int wid = threadIdx.x >> 6;
  __syncthreads();
  if ((threadIdx.x & 63) == 0) { sbuf[wid] = s; sbuf[4 + wid] = s2; }
  __syncthreads();
  float su = sbuf[0] + sbuf[1] + sbuf[2] + sbuf[3];
  float sq = sbuf[4] + sbuf[5] + sbuf[6] + sbuf[7];
  float mu = su / (float)D;
  float var = sq / (float)D - mu * mu;
  float rstd = rsqrtf(var + 1e-5f);
#pragma unroll
  for (int ii = 0; ii < 4; ii++) {
    int i = threadIdx.x + ii * 256;
    if (i < ocols)
      orow[i] = (i < D) ? f2bf((vv[ii] - mu) * rstd * g[i] + bta[i]) : 0;
  }
}

// ---------------------------------------------------------------------------
// attn v12 = v11 + serial-chain cuts (mask hoist / K half-prefetch / Psw
// split + batched reads / in-place softmax). See round theory.
// ---------------------------------------------------------------------------
__global__ __launch_bounds__(128, 2) void attn_mfma12(
    const unsigned short* __restrict__ Qall,
    const unsigned short* __restrict__ Kn,
    const unsigned short* __restrict__ Kr,
    const unsigned short* __restrict__ Vb,
    unsigned short* __restrict__ y)
{
  __shared__ __align__(16) unsigned short Pswb[4608];  // 2 waves x 2 grp x 1152
  const int id = (int)blockIdx.x;
  const int bhid = id & 31;
  const int s = id >> 5;                 // 0..31
  const int xx = s & 7, quad = s >> 3;
  const int a = (quad == 0) ? (31 - xx) : (quad == 1) ? (23 - xx)
              : (quad == 2) ? (xx + 8) : xx;   // q-tile: rows [a*64, a*64+64)
  const int h = bhid & 15, b = bhid >> 4;
  const int tid = threadIdx.x;
  const int w = tid >> 6, lane = tid & 63, q = lane >> 4, r = lane & 15;
  const int bh = bhid;

  const unsigned short* KnT0 = Kn + (size_t)bh * 131072;   // 32kt x 4096
  const unsigned short* KrT0 = Kr + (size_t)b * 131072;
  const unsigned short* VT0  = Vb + (size_t)bh * 262144;   // 32kt x 8192
  unsigned short* Psw0 = Pswb + w * 2304;
  unsigned short* Psw1 = Psw0 + 1152;

  short8 qb[2][4];
#pragma unroll
  for (int g = 0; g < 2; g++) {
    const unsigned short* Qrow =
        Qall + ((size_t)bh * T_SEQ + (size_t)a * 64 + w * 32 + g * 16 + r) * 128 + q * 8;
#pragma unroll
    for (int c = 0; c < 4; c++) qb[g][c] = *(const short8*)(Qrow + c * 32);
  }

  floatx4 oacc[2][8];
#pragma unroll
  for (int g = 0; g < 2; g++)
#pragma unroll
    for (int jd = 0; jd < 8; jd++) oacc[g][jd] = (floatx4){0.f, 0.f, 0.f, 0.f};
  float m_i[2] = {-3.0e38f, -3.0e38f}, l_i[2] = {0.f, 0.f};

  // persistent Kn-half prefetch (c = 0,1), preloaded for kt=0
  short8 akn[2][4];
#pragma unroll
  for (int c = 0; c < 2; c++)
#pragma unroll
    for (int j = 0; j < 4; j++)
      akn[c][j] = *(const short8*)&KnT0[c * 2048 + (j * 16 + r) * 32 + q * 8];

  for (int kt = 0; kt <= a; kt++) {
    const unsigned short* KrT = KrT0 + kt * 4096;
    const unsigned short* VT  = VT0 + kt * 8192;

    // Kr half loads issue now; ready Kn-half MFMAs cover their latency
    short8 akr[2][4];
#pragma unroll
    for (int c = 0; c < 2; c++)
#pragma unroll
      for (int j = 0; j < 4; j++)
        akr[c][j] = *(const short8*)&KrT[c * 2048 + (j * 16 + r) * 32 + q * 8];

    floatx4 sacc[2][4];
#pragma unroll
    for (int g = 0; g < 2; g++)
#pragma unroll
      for (int j = 0; j < 4; j++) sacc[g][j] = (floatx4){0.f, 0.f, 0.f, 0.f};

    __builtin_amdgcn_s_setprio(1);
#pragma unroll
    for (int c = 0; c < 2; c++)
#pragma unroll
      for (int g = 0; g < 2; g++)
#pragma unroll
        for (int j = 0; j < 4; j++)
          sacc[g][j] = __builtin_amdgcn_mfma_f32_16x16x32_bf16(akn[c][j], qb[g][c], sacc[g][j], 0, 0, 0);
#pragma unroll
    for (int c = 0; c < 2; c++)
#pragma unroll
      for (int g = 0; g < 2; g++)
#pragma unroll
        for (int j = 0; j < 4; j++)
          sacc[g][j] = __builtin_amdgcn_mfma_f32_16x16x32_bf16(akr[c][j], qb[g][c + 2], sacc[g][j], 0, 0, 0);
    __builtin_amdgcn_s_setprio(0);

    // V loads — latency hides under softmax
    short8 vb[2][8];
#pragma unroll
    for (int c2 = 0; c2 < 2; c2++)
#pragma unroll
      for (int jd = 0; jd < 8; jd++)
        vb[c2][jd] = *(const short8*)&VT[c2 * 4096 + (jd * 16 + r) * 32 + q * 8];

    // Kn-half prefetch for next iteration — hides under softmax+PV
    if (kt < a) {
      const unsigned short* KnN = KnT0 + (kt + 1) * 4096;
#pragma unroll
      for (int c = 0; c < 2; c++)
#pragma unroll
        for (int j = 0; j < 4; j++)
          akn[c][j] = *(const short8*)&KnN[c * 2048 + (j * 16 + r) * 32 + q * 8];
    }

#pragma unroll
    for (int g = 0; g < 2; g++) {
      if (kt == a) {   // masking only possible on the diagonal tile
        const int rel = w * 32 + g * 16 + r;
#pragma unroll
        for (int j = 0; j < 4; j++)
#pragma unroll
          for (int v = 0; v < 4; v++)
            if (j * 16 + q * 4 + v > rel) sacc[g][j][v] = -3.0e38f;
      }
      // tree-reduce max (in place)
      float tm[8];
#pragma unroll
      for (int j = 0; j < 2; j++)
#pragma unroll
        for (int v = 0; v < 4; v++)
          tm[j * 4 + v] = fmaxf(sacc[g][j][v], sacc[g][j + 2][v]);
#pragma unroll
      for (int t = 0; t < 4; t++) tm[t] = fmaxf(tm[t], tm[t + 4]);
      float rm = fmaxf(fmaxf(tm[0], tm[1]), fmaxf(tm[2], tm[3]));
      rm = fmaxf(rm, __shfl_xor(rm, 16, 64));
      rm = fmaxf(rm, __shfl_xor(rm, 32, 64));
      if (__any(rm > m_i[g] + 8.f)) {
        float mnew = fmaxf(m_i[g], rm);
        float alpha = exp2f(m_i[g] - mnew);
        m_i[g] = mnew;
        l_i[g] *= alpha;
#pragma unroll
        for (int jd = 0; jd < 8; jd++) {
          oacc[g][jd][0] *= alpha; oacc[g][jd][1] *= alpha;
          oacc[g][jd][2] *= alpha; oacc[g][jd][3] *= alpha;
        }
      }
      float p[16];
#pragma unroll
      for (int j = 0; j < 4; j++)
#pragma unroll
        for (int v = 0; v < 4; v++)
          p[j * 4 + v] = exp2f(sacc[g][j][v] - m_i[g]);
      float ts[8];
#pragma unroll
      for (int t = 0; t < 8; t++) ts[t] = p[t] + p[t + 8];
#pragma unroll
      for (int t = 0; t < 4; t++) ts[t] = ts[t] + ts[t + 4];
      float rsum = (ts[0] + ts[1]) + (ts[2] + ts[3]);
      rsum += __shfl_xor(rsum, 16, 64);
      rsum += __shfl_xor(rsum, 32, 64);
      l_i[g] += rsum;
      unsigned short* Pg = g ? Psw1 : Psw0;
#pragma unroll
      for (int j = 0; j < 4; j++) {
        unsigned int lo = (unsigned int)f2bf_fast(p[j * 4 + 0]) |
                          ((unsigned int)f2bf_fast(p[j * 4 + 1]) << 16);
        unsigned int hi = (unsigned int)f2bf_fast(p[j * 4 + 2]) |
                          ((unsigned int)f2bf_fast(p[j * 4 + 3]) << 16);
        uint2v pk; pk[0] = lo; pk[1] = hi;
        *(uint2v*)&Pg[r * 72 + j * 16 + q * 4] = pk;
      }
    }

    // batched pb reads: g=0's write->read gap covered by g=1's softmax
    short8 pb[2][2];
    pb[0][0] = *(const short8*)&Psw0[r * 72 + q * 8];
    pb[0][1] = *(const short8*)&Psw0[r * 72 + 32 + q * 8];
    pb[1][0] = *(const short8*)&Psw1[r * 72 + q * 8];
    pb[1][1] = *(const short8*)&Psw1[r * 72 + 32 + q * 8];

    __builtin_amdgcn_s_setprio(1);
#pragma unroll
    for (int c2 = 0; c2 < 2; c2++) {
#pragma unroll
      for (int jd = 0; jd < 8; jd++) {
        oacc[0][jd] = __builtin_amdgcn_mfma_f32_16x16x32_bf16(vb[c2][jd], pb[0][c2], oacc[0][jd], 0, 0, 0);
        oacc[1][jd] = __builtin_amdgcn_mfma_f32_16x16x32_bf16(vb[c2][jd], pb[1][c2], oacc[1][jd], 0, 0, 0);
      }
    }
    __builtin_amdgcn_s_setprio(0);
  }

#pragma unroll
  for (int g = 0; g < 2; g++) {
    float inv = 1.0f / l_i[g];
    unsigned short* yr =
        y + ((size_t)(b * T_SEQ) + (size_t)a * 64 + w * 32 + g * 16 + r) * DM + h * 128;
#pragma unroll
    for (int jd = 0; jd < 8; jd++) {
      unsigned short o0 = f2bf(oacc[g][jd][0] * inv);
      unsigned short o1 = f2bf(oacc[g][jd][1] * inv);
      unsigned short o2 = f2bf(oacc[g][jd][2] * inv);
      unsigned short o3 = f2bf(oacc[g][jd][3] * inv);
      unsigned int lo = (unsigned int)o0 | ((unsigned int)o1 << 16);
      unsigned int hi = (unsigned int)o2 | ((unsigned int)o3 << 16);
      unsigned int* dst = (unsigned int*)(yr + jd * 16 + q * 4);
      dst[0] = lo; dst[1] = hi;
    }
  }
}

// ---------------------------------------------------------------------------
extern "C" void kernel_launch(void* const* d_in, const int* in_sizes, int n_in,
                              void* d_out, int out_size, void* d_ws, size_t ws_size,
                              hipStream_t stream) {
  const float* x      = (const float*)d_in[0];
  const float* Wdq_w  = (const float*)d_in[1];
  const float* Wdq_b  = (const float*)d_in[2];
  const float* qn_g   = (const float*)d_in[3];
  const float* qn_b   = (const float*)d_in[4];
  const float* Wuq_w  = (const float*)d_in[5];
  const float* Wuq_b  = (const float*)d_in[6];
  const float* Wdkv_w = (const float*)d_in[7];
  const float* Wdkv_b = (const float*)d_in[8];
  const float* kvn_g  = (const float*)d_in[9];
  const float* kvn_b  = (const float*)d_in[10];
  const float* Wukv_w = (const float*)d_in[11];
  const float* Wukv_b = (const float*)d_in[12];
  const float* Wo_w   = (const float*)d_in[13];
  const float* Wo_b   = (const float*)d_in[14];
  float* out = (float*)d_out;

  float* ws = (float*)d_ws;
  unsigned short* x_bf    = (unsigned short*)(ws);              // dies after dqkv gemm
  unsigned short* y_bf    = (unsigned short*)(ws);              // alias: attn output
  unsigned short* Wqkv_bf = (unsigned short*)(ws + 4194304);    // 1792x2048
  unsigned short* Wuq_bf  = (unsigned short*)(ws + 6029312);    // 2048x704
  unsigned short* Wukv_bf = (unsigned short*)(ws + 6750208);    // 3072x1024
  float* bias_qkv = ws + 8323072;                               // 1792
  float* p0       = ws + 8324864;                               // 4096x1792 fp32
  unsigned short* c_q_bf = (unsigned short*)(ws + 23004928);    // 4096x704
  unsigned short* kvn_bf = (unsigned short*)(ws + 24446720);    // 4096x1024
  unsigned short* Q_all  = (unsigned short*)(ws + 26543872);    // 2x16x2048x128
  unsigned short* Kn_blk = (unsigned short*)(ws + 30738176);    // 32bh x 32kt x 4096
  unsigned short* Kr_blk = (unsigned short*)(ws + 32835328);    // 2b x 32kt x 4096
  unsigned short* V_blk  = (unsigned short*)(ws + 32966400);    // 32bh x 32kt x 8192
  unsigned short* Wo_bf  = (unsigned short*)(ws + 37160704);    // 2048x2048

  dim3 blk(256);

  prep_all<<<20359, blk, 0, stream>>>(x, Wdq_w, Wdkv_w, Wuq_w, Wukv_w, Wo_w,
                                      Wdq_b, Wdkv_b,
                                      x_bf, Wqkv_bf, Wuq_bf, Wukv_bf, Wo_bf,
                                      bias_qkv);
  gemm_dqkv<<<dim3(14, 32), blk, 0, stream>>>(x_bf, Wqkv_bf, p0);
  ln_dual_r<<<8704, blk, 0, stream>>>(p0, bias_qkv, c_q_bf, kvn_bf, Kr_blk,
                                      qn_g, qn_b, kvn_g, kvn_b);
  gemm_up_fused<<<dim3(40, 32), blk, 0, stream>>>(c_q_bf, Wuq_bf, Wuq_b, Q_all,
                                                  kvn_bf, Wukv_bf, Wukv_b,
                                                  Kn_blk, V_blk);
  attn_mfma12<<<1024, dim3(128), 0, stream>>>(Q_all, Kn_blk, Kr_blk, V_blk, y_bf);
  gemm_wo64<<<dim3(16, 32), blk, 0, stream>>>(y_bf, Wo_bf, Wo_b, out);
}